// Round 3
// 1280.576 us; speedup vs baseline: 1.0034x; 1.0034x over previous
//
#include <hip/hip_runtime.h>
#include <hip/hip_bf16.h>

constexpr int Sq = 256;
constexpr int Hq = 768;

typedef __attribute__((ext_vector_type(4))) float f32x4;
typedef __attribute__((ext_vector_type(8))) short bf16x8;

__device__ __forceinline__ float bf2f(unsigned short u) {
  unsigned int x = ((unsigned int)u) << 16;
  float f;
  __builtin_memcpy(&f, &x, 4);
  return f;
}
__device__ __forceinline__ unsigned short f2bf(float f) {
  unsigned int x;
  __builtin_memcpy(&x, &f, 4);
  unsigned int lsb = (x >> 16) & 1u;
  x += 0x7fffu + lsb;  // round-to-nearest-even
  return (unsigned short)(x >> 16);
}
__device__ __forceinline__ void cvt4split(float4 v, ushort4& h, ushort4& l) {
  h.x = f2bf(v.x);
  l.x = f2bf(v.x - bf2f(h.x));
  h.y = f2bf(v.y);
  l.y = f2bf(v.y - bf2f(h.y));
  h.z = f2bf(v.z);
  l.z = f2bf(v.z - bf2f(h.z));
  h.w = f2bf(v.w);
  l.w = f2bf(v.w - bf2f(h.w));
}

// For option b (within its group of 4), the k-th other option (ascending).
__device__ __forceinline__ int other_of(int b, int k) {
  int i = b & 3;
  int jl = k + (k >= i ? 1 : 0);
  return (b & ~3) + jl;
}

constexpr int LDP = 40;  // padded LDS K-stride (elements); 80B pitch keeps 16B align

// Stage [ROWS x 32] fp32 tile -> bf16 LDS (single rounding).
template <int ROWS>
__device__ __forceinline__ void stage_f32(const float* __restrict__ G, int lda, int kk,
                                          unsigned short* __restrict__ S, int tid) {
#pragma unroll
  for (int pp = 0; pp < ROWS / 32; ++pp) {
    int idx = tid + pp * 256;
    int row = idx >> 3;
    int c4 = (idx & 7) << 2;
    float4 v = *(const float4*)(G + (long)row * lda + kk + c4);
    ushort4 o;
    o.x = f2bf(v.x);
    o.y = f2bf(v.y);
    o.z = f2bf(v.z);
    o.w = f2bf(v.w);
    *(ushort4*)(&S[row * LDP + c4]) = o;
  }
}

// Stage [ROWS x 32] fp32 tile -> hi/lo bf16 LDS pair (split precision).
template <int ROWS>
__device__ __forceinline__ void stage_f32_split(const float* __restrict__ G, int lda, int kk,
                                                unsigned short* __restrict__ Sh,
                                                unsigned short* __restrict__ Sl, int tid) {
#pragma unroll
  for (int pp = 0; pp < ROWS / 32; ++pp) {
    int idx = tid + pp * 256;
    int row = idx >> 3;
    int c4 = (idx & 7) << 2;
    float4 v = *(const float4*)(G + (long)row * lda + kk + c4);
    ushort4 h, l;
    cvt4split(v, h, l);
    *(ushort4*)(&Sh[row * LDP + c4]) = h;
    *(ushort4*)(&Sl[row * LDP + c4]) = l;
  }
}

// Stage [ROWS x 32] bf16 tile -> bf16 LDS (pure copy).
template <int ROWS>
__device__ __forceinline__ void stage_b16(const unsigned short* __restrict__ G, int lda, int kk,
                                          unsigned short* __restrict__ S, int tid) {
#pragma unroll
  for (int pp = 0; pp < ROWS / 64; ++pp) {
    int idx = tid + pp * 256;
    int row = idx >> 2;
    int c8 = (idx & 3) << 3;
    uint4 v = *(const uint4*)(G + (long)row * lda + kk + c8);
    *(uint4*)(&S[row * LDP + c8]) = v;
  }
}

// ---------------------------------------------------------------------------
// Precast kernel: p -> hi/lo bf16 (memory-bound, once at graph front).
// ---------------------------------------------------------------------------
__global__ __launch_bounds__(256) void k_prep_p(const float* __restrict__ p,
                                                unsigned short* __restrict__ ph,
                                                unsigned short* __restrict__ pl) {
  const long n4 = (long)128 * Sq * Hq / 4;
  const long stride = (long)gridDim.x * blockDim.x;
  for (long i = (long)blockIdx.x * blockDim.x + threadIdx.x; i < n4; i += stride) {
    float4 v = ((const float4*)p)[i];
    ushort4 h, l;
    cvt4split(v, h, l);
    ((ushort4*)ph)[i] = h;
    ((ushort4*)pl)[i] = l;
  }
}

// ---------------------------------------------------------------------------
// Tiled MFMA GEMM core: C[128x128] = A[128xK] * B^T. B is [N,K] row-major.
// A: fp32 (converted) or bf16 (copy). B: fp32 (converted) or bf16 (copy).
// ---------------------------------------------------------------------------
template <bool A_F32, bool B_F32>
__device__ __forceinline__ void gemm_tile(const void* __restrict__ Av, int lda,
                                          const void* __restrict__ Bv, int ldb, int K,
                                          f32x4 acc[4][4]) {
  __shared__ unsigned short As[128 * LDP];
  __shared__ unsigned short Bs[128 * LDP];
  const int tid = threadIdx.x;
  const int lane = tid & 63;
  const int wid = tid >> 6;
  const int wr = (wid >> 1) << 6;
  const int wc = (wid & 1) << 6;
  const int q4 = lane >> 4;
  const int l16 = lane & 15;

#pragma unroll
  for (int mi = 0; mi < 4; ++mi)
#pragma unroll
    for (int ni = 0; ni < 4; ++ni) acc[mi][ni] = (f32x4){0.f, 0.f, 0.f, 0.f};

  for (int kk = 0; kk < K; kk += 32) {
    __syncthreads();
    if constexpr (A_F32)
      stage_f32<128>((const float*)Av, lda, kk, As, tid);
    else
      stage_b16<128>((const unsigned short*)Av, lda, kk, As, tid);
    if constexpr (B_F32)
      stage_f32<128>((const float*)Bv, ldb, kk, Bs, tid);
    else
      stage_b16<128>((const unsigned short*)Bv, ldb, kk, Bs, tid);
    __syncthreads();
    bf16x8 af[4], bfr[4];
#pragma unroll
    for (int mi = 0; mi < 4; ++mi)
      af[mi] = *(const bf16x8*)(&As[(wr + mi * 16 + l16) * LDP + (q4 << 3)]);
#pragma unroll
    for (int ni = 0; ni < 4; ++ni)
      bfr[ni] = *(const bf16x8*)(&Bs[(wc + ni * 16 + l16) * LDP + (q4 << 3)]);
#pragma unroll
    for (int mi = 0; mi < 4; ++mi)
#pragma unroll
      for (int ni = 0; ni < 4; ++ni)
        acc[mi][ni] =
            __builtin_amdgcn_mfma_f32_16x16x32_bf16(af[mi], bfr[ni], acc[mi][ni], 0, 0, 0);
  }
}

// Split-precision GEMM core: A is precast hi/lo bf16 (copies); B is fp32
// split-staged on the fly. 3 MFMA chains.
__device__ __forceinline__ void gemm_tile_split(const unsigned short* __restrict__ Ahp,
                                                const unsigned short* __restrict__ Alp, int lda,
                                                const float* __restrict__ B, int ldb, int K,
                                                f32x4 acc[4][4]) {
  __shared__ unsigned short Ah[128 * LDP], Al[128 * LDP];
  __shared__ unsigned short Bh[128 * LDP], Bl[128 * LDP];
  const int tid = threadIdx.x;
  const int lane = tid & 63;
  const int wid = tid >> 6;
  const int wr = (wid >> 1) << 6;
  const int wc = (wid & 1) << 6;
  const int q4 = lane >> 4;
  const int l16 = lane & 15;

#pragma unroll
  for (int mi = 0; mi < 4; ++mi)
#pragma unroll
    for (int ni = 0; ni < 4; ++ni) acc[mi][ni] = (f32x4){0.f, 0.f, 0.f, 0.f};

  for (int kk = 0; kk < K; kk += 32) {
    __syncthreads();
    stage_b16<128>(Ahp, lda, kk, Ah, tid);
    stage_b16<128>(Alp, lda, kk, Al, tid);
    stage_f32_split<128>(B, ldb, kk, Bh, Bl, tid);
    __syncthreads();
    bf16x8 ah[4], al[4], bh[4], bl[4];
#pragma unroll
    for (int mi = 0; mi < 4; ++mi) {
      ah[mi] = *(const bf16x8*)(&Ah[(wr + mi * 16 + l16) * LDP + (q4 << 3)]);
      al[mi] = *(const bf16x8*)(&Al[(wr + mi * 16 + l16) * LDP + (q4 << 3)]);
    }
#pragma unroll
    for (int ni = 0; ni < 4; ++ni) {
      bh[ni] = *(const bf16x8*)(&Bh[(wc + ni * 16 + l16) * LDP + (q4 << 3)]);
      bl[ni] = *(const bf16x8*)(&Bl[(wc + ni * 16 + l16) * LDP + (q4 << 3)]);
    }
#pragma unroll
    for (int mi = 0; mi < 4; ++mi)
#pragma unroll
      for (int ni = 0; ni < 4; ++ni) {
        acc[mi][ni] =
            __builtin_amdgcn_mfma_f32_16x16x32_bf16(ah[mi], bh[ni], acc[mi][ni], 0, 0, 0);
        acc[mi][ni] =
            __builtin_amdgcn_mfma_f32_16x16x32_bf16(ah[mi], bl[ni], acc[mi][ni], 0, 0, 0);
        acc[mi][ni] =
            __builtin_amdgcn_mfma_f32_16x16x32_bf16(al[mi], bh[ni], acc[mi][ni], 0, 0, 0);
      }
  }
}

// C/D layout (m89-verified): col=lane&15, row=(lane>>4)*4+reg.
#define EPI_BEGIN()                                        \
  const int lane = threadIdx.x & 63;                       \
  const int wid = threadIdx.x >> 6;                        \
  const int wr = (wid >> 1) << 6, wc = (wid & 1) << 6;     \
  const int q4 = lane >> 4, l16 = lane & 15;               \
  _Pragma("unroll") for (int mi = 0; mi < 4; ++mi)         \
      _Pragma("unroll") for (int ni = 0; ni < 4; ++ni)

// ---------------------------------------------------------------------------
// K1: tp = p @ Wt^T + bt  (split precision, stored as hi/lo bf16 pair)
__global__ __launch_bounds__(256) void k_tp(const unsigned short* __restrict__ ph,
                                            const unsigned short* __restrict__ pl,
                                            const float* __restrict__ Wt,
                                            const float* __restrict__ bt,
                                            unsigned short* __restrict__ tph,
                                            unsigned short* __restrict__ tpl) {
  const int bm = blockIdx.x * 128, bn = blockIdx.y * 128;
  f32x4 acc[4][4];
  gemm_tile_split(ph + (long)bm * Hq, pl + (long)bm * Hq, Hq, Wt + (long)bn * Hq, Hq, Hq, acc);
  const bool has_lo = (tpl != nullptr);
  EPI_BEGIN() {
    int col = bn + wc + ni * 16 + l16;
    float bv = bt[col];
#pragma unroll
    for (int r = 0; r < 4; ++r) {
      int row = bm + wr + mi * 16 + q4 * 4 + r;
      float v = acc[mi][ni][r] + bv;
      unsigned short h = f2bf(v);
      tph[(long)row * Hq + col] = h;
      if (has_lo) tpl[(long)row * Hq + col] = f2bf(v - bf2f(h));
    }
  }
}

// K2: pdT[b][h][s] = (p @ Wd^T)[b*256+s][h]  (transposed store; bd added in k_occ)
__global__ __launch_bounds__(256) void k_pd(const unsigned short* __restrict__ ph,
                                            const float* __restrict__ Wd,
                                            unsigned short* __restrict__ pdT) {
  const int bm = blockIdx.x * 128, bn = blockIdx.y * 128;
  f32x4 acc[4][4];
  gemm_tile<false, true>(ph + (long)bm * Hq, Hq, Wd + (long)bn * Hq, Hq, Hq, acc);
  EPI_BEGIN() {
    int col = bn + wc + ni * 16 + l16;          // h index
    int rbase = bm + wr + mi * 16 + (q4 << 2);  // global row = b*256 + s
    int b = rbase >> 8, s0 = rbase & 255;
    ushort4 o;
    o.x = f2bf(acc[mi][ni][0]);
    o.y = f2bf(acc[mi][ni][1]);
    o.z = f2bf(acc[mi][ni][2]);
    o.w = f2bf(acc[mi][ni][3]);
    *(ushort4*)(pdT + ((long)b * Hq + col) * Sq + s0) = o;
  }
}

// ---------------------------------------------------------------------------
// K3 (fused): sm[b,k] = masked_softmax(p[b] @ tp[j]^T)  -> bf16 [384,256,256]
// Split-precision scores: p hi/lo (precast) x tp hi/lo (precomputed).
// Block: 128 rows x 256 cols. 4 waves: 2 row-groups x 2 col-halves.
// ---------------------------------------------------------------------------
__global__ __launch_bounds__(256, 1) void k_attsm(const unsigned short* __restrict__ ph,
                                                  const unsigned short* __restrict__ pl,
                                                  const unsigned short* __restrict__ tph,
                                                  const unsigned short* __restrict__ tpl,
                                                  const int* __restrict__ olen,
                                                  unsigned short* __restrict__ sm) {
  const int batch = blockIdx.y;
  const int b = batch / 3, k = batch % 3;
  const int j = other_of(b, k);
  const int bm = blockIdx.x * 128;
  const int len = olen[j] + 1;  // key length, 1..255
  const int tid = threadIdx.x;
  const int lane = tid & 63;
  const int wid = tid >> 6;
  const int wr = (wid >> 1) << 6;  // 0 or 64
  const int wc = (wid & 1) << 7;   // 0 or 128
  const int half = wid & 1;
  const int q4 = lane >> 4, l16 = lane & 15;
  const bool has_lo = (tpl != nullptr);

  __shared__ unsigned short Ah[128 * LDP], Al[128 * LDP];
  __shared__ unsigned short Bh[256 * LDP], Bl[256 * LDP];
  __shared__ float red[256];  // 128 rows x 2 column-halves

  const unsigned short* Aph = ph + ((long)b * Sq + bm) * Hq;
  const unsigned short* Apl = pl + ((long)b * Sq + bm) * Hq;
  const unsigned short* Bph = tph + (long)j * Sq * Hq;
  const unsigned short* Bpl = has_lo ? tpl + (long)j * Sq * Hq : nullptr;

  f32x4 acc[4][8];
#pragma unroll
  for (int mi = 0; mi < 4; ++mi)
#pragma unroll
    for (int ni = 0; ni < 8; ++ni) acc[mi][ni] = (f32x4){0.f, 0.f, 0.f, 0.f};

  for (int kk = 0; kk < Hq; kk += 32) {
    __syncthreads();
    stage_b16<128>(Aph, Hq, kk, Ah, tid);
    stage_b16<128>(Apl, Hq, kk, Al, tid);
    stage_b16<256>(Bph, Hq, kk, Bh, tid);
    if (has_lo) stage_b16<256>(Bpl, Hq, kk, Bl, tid);
    __syncthreads();
    bf16x8 ah[4], al[4];
#pragma unroll
    for (int mi = 0; mi < 4; ++mi) {
      ah[mi] = *(const bf16x8*)(&Ah[(wr + mi * 16 + l16) * LDP + (q4 << 3)]);
      al[mi] = *(const bf16x8*)(&Al[(wr + mi * 16 + l16) * LDP + (q4 << 3)]);
    }
#pragma unroll
    for (int ni = 0; ni < 8; ++ni) {
      bf16x8 bh = *(const bf16x8*)(&Bh[(wc + ni * 16 + l16) * LDP + (q4 << 3)]);
#pragma unroll
      for (int mi = 0; mi < 4; ++mi) {
        acc[mi][ni] = __builtin_amdgcn_mfma_f32_16x16x32_bf16(ah[mi], bh, acc[mi][ni], 0, 0, 0);
        acc[mi][ni] = __builtin_amdgcn_mfma_f32_16x16x32_bf16(al[mi], bh, acc[mi][ni], 0, 0, 0);
      }
      if (has_lo) {
        bf16x8 bl = *(const bf16x8*)(&Bl[(wc + ni * 16 + l16) * LDP + (q4 << 3)]);
#pragma unroll
        for (int mi = 0; mi < 4; ++mi)
          acc[mi][ni] = __builtin_amdgcn_mfma_f32_16x16x32_bf16(ah[mi], bl, acc[mi][ni], 0, 0, 0);
      }
    }
  }

  // ---- reference-faithful masked softmax, numerically stable ----
  bool cm[8];
#pragma unroll
  for (int ni = 0; ni < 8; ++ni) cm[ni] = (wc + ni * 16 + l16) >= len;
#pragma unroll
  for (int mi = 0; mi < 4; ++mi)
#pragma unroll
    for (int ni = 0; ni < 8; ++ni)
      if (cm[ni]) acc[mi][ni] = (f32x4){0.f, 0.f, 0.f, 0.f};  // score*mask

  float rmax[4][4];
#pragma unroll
  for (int mi = 0; mi < 4; ++mi)
#pragma unroll
    for (int r = 0; r < 4; ++r) {
      float m = acc[mi][0][r];
#pragma unroll
      for (int ni = 1; ni < 8; ++ni) m = fmaxf(m, acc[mi][ni][r]);
#pragma unroll
      for (int off = 1; off <= 8; off <<= 1) m = fmaxf(m, __shfl_xor(m, off, 64));
      rmax[mi][r] = m;  // max over this col-half (includes masked zeros)
    }
  if (l16 == 0) {
#pragma unroll
    for (int mi = 0; mi < 4; ++mi)
#pragma unroll
      for (int r = 0; r < 4; ++r) red[(wr + mi * 16 + q4 * 4 + r) * 2 + half] = rmax[mi][r];
  }
  __syncthreads();
#pragma unroll
  for (int mi = 0; mi < 4; ++mi)
#pragma unroll
    for (int r = 0; r < 4; ++r) {
      int row = wr + mi * 16 + q4 * 4 + r;
      rmax[mi][r] = fmaxf(red[row * 2], red[row * 2 + 1]);
    }
  __syncthreads();  // red reads done before reuse

  // su = sum of exp over UNMASKED entries only (stable).
  float rsum[4][4];
#pragma unroll
  for (int mi = 0; mi < 4; ++mi)
#pragma unroll
    for (int r = 0; r < 4; ++r) rsum[mi][r] = 0.f;
#pragma unroll
  for (int mi = 0; mi < 4; ++mi)
#pragma unroll
    for (int ni = 0; ni < 8; ++ni)
#pragma unroll
      for (int r = 0; r < 4; ++r) {
        float e = __expf(acc[mi][ni][r] - rmax[mi][r]);
        acc[mi][ni][r] = e;
        if (!cm[ni]) rsum[mi][r] += e;
      }
#pragma unroll
  for (int mi = 0; mi < 4; ++mi)
#pragma unroll
    for (int r = 0; r < 4; ++r) {
#pragma unroll
      for (int off = 1; off <= 8; off <<= 1) rsum[mi][r] += __shfl_xor(rsum[mi][r], off, 64);
    }
  if (l16 == 0) {
#pragma unroll
    for (int mi = 0; mi < 4; ++mi)
#pragma unroll
      for (int r = 0; r < 4; ++r) red[(wr + mi * 16 + q4 * 4 + r) * 2 + half] = rsum[mi][r];
  }
  __syncthreads();

  const float nm = (float)(Sq - len);
  unsigned short* srow = sm + (long)batch * Sq * Sq;
#pragma unroll
  for (int mi = 0; mi < 4; ++mi)
#pragma unroll
    for (int r = 0; r < 4; ++r) {
      int row = wr + mi * 16 + q4 * 4 + r;
      float su = red[row * 2] + red[row * 2 + 1];  // unmasked sum (>=0)
      float em = __expf(-rmax[mi][r]);             // masked entries' e
      float zs = su + nm * em;                     // full softmax denom
      float fs = 1.f / (su + 1e-13f * zs);         // stable renorm
      unsigned short* o = srow + (long)(bm + row) * Sq + wc + l16;
#pragma unroll
      for (int ni = 0; ni < 8; ++ni)
        o[ni * 16] = f2bf(cm[ni] ? 0.f : acc[mi][ni][r] * fs);
    }
}

// K4: occ[(b,s,k),:] = relu(sm[b,k] @ pd[j] + bd)   rows in (b,s,k) order
// pd consumed via pdT[j][h][s]: B[N=h,K=s] row-major -> fast linear staging.
__global__ __launch_bounds__(256) void k_occ(const unsigned short* __restrict__ sm,
                                             const unsigned short* __restrict__ pdT,
                                             const float* __restrict__ bd,
                                             unsigned short* __restrict__ occ) {
  const int batch = blockIdx.z;
  const int b = batch / 3, k = batch % 3;
  const int j = other_of(b, k);
  const int bm = blockIdx.x * 128, bn = blockIdx.y * 128;
  f32x4 acc[4][4];
  gemm_tile<false, false>(sm + (long)batch * Sq * Sq + (long)bm * Sq, Sq,
                          pdT + ((long)j * Hq + bn) * Sq, Sq, Sq, acc);
  EPI_BEGIN() {
    int col = bn + wc + ni * 16 + l16;
    float bv = bd[col];
#pragma unroll
    for (int r = 0; r < 4; ++r) {
      int s = bm + wr + mi * 16 + q4 * 4 + r;
      occ[((long)(b * Sq + s) * 3 + k) * Hq + col] = f2bf(fmaxf(acc[mi][ni][r] + bv, 0.f));
    }
  }
}

// K5: oc = occ_flat[32768,2304] @ Wd3^T + bd3  -> bf16
__global__ __launch_bounds__(256) void k_oc(const unsigned short* __restrict__ occ,
                                            const float* __restrict__ Wd3,
                                            const float* __restrict__ bd3,
                                            unsigned short* __restrict__ oc) {
  const int bm = blockIdx.x * 128, bn = blockIdx.y * 128;
  f32x4 acc[4][4];
  gemm_tile<false, true>(occ + (long)bm * 3 * Hq, 3 * Hq, Wd3 + (long)bn * 3 * Hq, 3 * Hq,
                         3 * Hq, acc);
  EPI_BEGIN() {
    int col = bn + wc + ni * 16 + l16;
    float bv = bd3[col];
#pragma unroll
    for (int r = 0; r < 4; ++r) {
      int row = bm + wr + mi * 16 + q4 * 4 + r;
      oc[(long)row * Hq + col] = f2bf(acc[mi][ni][r] + bv);
    }
  }
}

// K6: g1 = oc @ W1^T + b1 + b2  -> bf16
__global__ __launch_bounds__(256) void k_g1(const unsigned short* __restrict__ oc,
                                            const float* __restrict__ W1,
                                            const float* __restrict__ b1,
                                            const float* __restrict__ b2,
                                            unsigned short* __restrict__ g1) {
  const int bm = blockIdx.x * 128, bn = blockIdx.y * 128;
  f32x4 acc[4][4];
  gemm_tile<false, true>(oc + (long)bm * Hq, Hq, W1 + (long)bn * Hq, Hq, Hq, acc);
  EPI_BEGIN() {
    int col = bn + wc + ni * 16 + l16;
    float bv = b1[col] + b2[col];
#pragma unroll
    for (int r = 0; r < 4; ++r) {
      int row = bm + wr + mi * 16 + q4 * 4 + r;
      g1[(long)row * Hq + col] = f2bf(acc[mi][ni][r] + bv);
    }
  }
}

// K7: mid = sigmoid(g1 + p @ W2^T); out = p*mid + oc*(1-mid)  (fp32 out)
__global__ __launch_bounds__(256) void k_out(const float* __restrict__ p,
                                             const float* __restrict__ W2,
                                             const unsigned short* __restrict__ g1,
                                             const unsigned short* __restrict__ oc,
                                             float* __restrict__ out) {
  const int bm = blockIdx.x * 128, bn = blockIdx.y * 128;
  f32x4 acc[4][4];
  gemm_tile<true, true>(p + (long)bm * Hq, Hq, W2 + (long)bn * Hq, Hq, Hq, acc);
  EPI_BEGIN() {
    int col = bn + wc + ni * 16 + l16;
#pragma unroll
    for (int r = 0; r < 4; ++r) {
      int row = bm + wr + mi * 16 + q4 * 4 + r;
      long idx = (long)row * Hq + col;
      float g = acc[mi][ni][r] + bf2f(g1[idx]);
      float mid = 1.f / (1.f + __expf(-g));
      float pv = p[idx];
      float ov = bf2f(oc[idx]);
      out[idx] = pv * mid + ov * (1.f - mid);
    }
  }
}

// ---------------------------------------------------------------------------
extern "C" void kernel_launch(void* const* d_in, const int* in_sizes, int n_in, void* d_out,
                              int out_size, void* d_ws, size_t ws_size, hipStream_t stream) {
  const float* p = (const float*)d_in[0];
  const int* olen = (const int*)d_in[1];
  const float* Wt = (const float*)d_in[2];
  const float* bt = (const float*)d_in[3];
  const float* Wd = (const float*)d_in[4];
  const float* bd = (const float*)d_in[5];
  const float* Wd3 = (const float*)d_in[6];
  const float* bd3 = (const float*)d_in[7];
  const float* W1 = (const float*)d_in[8];
  const float* b1 = (const float*)d_in[9];
  const float* W2 = (const float*)d_in[10];
  const float* b2 = (const float*)d_in[11];
  float* out = (float*)d_out;

  char* ws = (char*)d_ws;
  const long U = 50331648L;  // 48 MiB unit
  unsigned short *tph, *tpl, *ph, *pl, *pdT, *sm, *occ, *oc, *g1;
  if (ws_size >= (size_t)(6 * U)) {
    // 288 MiB layout:
    //   slot0: tph (K1->K3), occ (K4->K5)
    //   slot1: tpl (K1->K3), occ
    //   slot2: pl  (prep->K3), occ
    //   slot3: ph  (prep->K3), oc (K5->K7)
    //   slot4: sm  (K3->K4),  g1 (K6->K7)
    //   slot5: pdT (K2->K4)
    tph = (unsigned short*)(ws + 0 * U);
    tpl = (unsigned short*)(ws + 1 * U);
    pl = (unsigned short*)(ws + 2 * U);
    ph = (unsigned short*)(ws + 3 * U);
    occ = (unsigned short*)(ws + 0 * U);
    oc = (unsigned short*)(ws + 3 * U);
    sm = (unsigned short*)(ws + 4 * U);
    g1 = (unsigned short*)(ws + 4 * U);
    pdT = (unsigned short*)(ws + 5 * U);
  } else {
    // 240 MiB fallback: drop tp_lo (p-split only in k_attsm).
    //   slot0: tph, occ   slot1: ph, occ   slot2: pl, occ
    //   slot3: pdT (K2->K4), oc (K5->K7)   slot4: sm, g1
    tph = (unsigned short*)(ws + 0 * U);
    tpl = nullptr;
    ph = (unsigned short*)(ws + 1 * U);
    pl = (unsigned short*)(ws + 2 * U);
    occ = (unsigned short*)(ws + 0 * U);
    pdT = (unsigned short*)(ws + 3 * U);
    oc = (unsigned short*)(ws + 3 * U);
    sm = (unsigned short*)(ws + 4 * U);
    g1 = (unsigned short*)(ws + 4 * U);
  }

  k_prep_p<<<2048, 256, 0, stream>>>(p, ph, pl);
  k_tp<<<dim3(256, 6), 256, 0, stream>>>(ph, pl, Wt, bt, tph, tpl);
  k_pd<<<dim3(256, 6), 256, 0, stream>>>(ph, Wd, pdT);
  k_attsm<<<dim3(2, 384), 256, 0, stream>>>(ph, pl, tph, tpl, olen, sm);
  k_occ<<<dim3(2, 6, 384), 256, 0, stream>>>(sm, pdT, bd, occ);
  k_oc<<<dim3(256, 6), 256, 0, stream>>>(occ, Wd3, bd3, oc);
  k_g1<<<dim3(256, 6), 256, 0, stream>>>(oc, W1, b1, b2, g1);
  k_out<<<dim3(256, 6), 256, 0, stream>>>(p, W2, g1, oc, out);
}

// Round 4
// 1162.960 us; speedup vs baseline: 1.1049x; 1.1011x over previous
//
#include <hip/hip_runtime.h>
#include <hip/hip_bf16.h>

constexpr int Sq = 256;
constexpr int Hq = 768;

typedef __attribute__((ext_vector_type(4))) float f32x4;
typedef __attribute__((ext_vector_type(8))) short bf16x8;

__device__ __forceinline__ float bf2f(unsigned short u) {
  unsigned int x = ((unsigned int)u) << 16;
  float f;
  __builtin_memcpy(&f, &x, 4);
  return f;
}
__device__ __forceinline__ unsigned short f2bf(float f) {
  unsigned int x;
  __builtin_memcpy(&x, &f, 4);
  unsigned int lsb = (x >> 16) & 1u;
  x += 0x7fffu + lsb;  // round-to-nearest-even
  return (unsigned short)(x >> 16);
}
__device__ __forceinline__ void cvt4split(float4 v, ushort4& h, ushort4& l) {
  h.x = f2bf(v.x);
  l.x = f2bf(v.x - bf2f(h.x));
  h.y = f2bf(v.y);
  l.y = f2bf(v.y - bf2f(h.y));
  h.z = f2bf(v.z);
  l.z = f2bf(v.z - bf2f(h.z));
  h.w = f2bf(v.w);
  l.w = f2bf(v.w - bf2f(h.w));
}

// For option b (within its group of 4), the k-th other option (ascending).
__device__ __forceinline__ int other_of(int b, int k) {
  int i = b & 3;
  int jl = k + (k >= i ? 1 : 0);
  return (b & ~3) + jl;
}

constexpr int LDP = 32;  // LINEAR K-stride (64B rows) — required by global_load_lds

// Row-dependent XOR swizzle (element units, 8-elem granules). Applied to the
// GLOBAL source of DMA staging, to VALU LDS writes, and to fragment reads.
// LDS[row][c] always holds G[row][c ^ swz8(row)]; reads XOR again -> identity.
__device__ __forceinline__ int swz8(int row) { return ((row >> 1) & 3) << 3; }

// Async 16B global -> LDS (DMA). Dest must be wave-uniform base + lane*16B.
__device__ __forceinline__ void gload16(const unsigned short* g, unsigned short* s) {
  __builtin_amdgcn_global_load_lds((const __attribute__((address_space(1))) unsigned int*)g,
                                   (__attribute__((address_space(3))) unsigned int*)s, 16, 0, 0);
}

// Stage [ROWS x 32] bf16 tile -> LDS via DMA, source pre-swizzled.
template <int ROWS>
__device__ __forceinline__ void dma_b16(const unsigned short* __restrict__ G, int lda, int kk,
                                        unsigned short* __restrict__ S, int tid) {
#pragma unroll
  for (int pp = 0; pp < ROWS / 64; ++pp) {
    int idx = tid + pp * 256;
    int row = idx >> 2;
    int c8 = ((idx & 3) << 3) ^ swz8(row);
    gload16(G + (long)row * lda + kk + c8, S + idx * 8);
  }
}

// Stage [ROWS x 32] fp32 tile -> bf16 LDS (single rounding), swizzled write.
template <int ROWS>
__device__ __forceinline__ void stage_f32(const float* __restrict__ G, int lda, int kk,
                                          unsigned short* __restrict__ S, int tid) {
#pragma unroll
  for (int pp = 0; pp < ROWS / 32; ++pp) {
    int idx = tid + pp * 256;
    int row = idx >> 3;
    int c4 = (idx & 7) << 2;
    float4 v = *(const float4*)(G + (long)row * lda + kk + c4);
    ushort4 o;
    o.x = f2bf(v.x);
    o.y = f2bf(v.y);
    o.z = f2bf(v.z);
    o.w = f2bf(v.w);
    *(ushort4*)(&S[row * LDP + (c4 ^ swz8(row))]) = o;
  }
}

// Stage [ROWS x 32] fp32 tile -> hi/lo bf16 LDS pair (split), swizzled write.
template <int ROWS>
__device__ __forceinline__ void stage_f32_split(const float* __restrict__ G, int lda, int kk,
                                                unsigned short* __restrict__ Sh,
                                                unsigned short* __restrict__ Sl, int tid) {
#pragma unroll
  for (int pp = 0; pp < ROWS / 32; ++pp) {
    int idx = tid + pp * 256;
    int row = idx >> 3;
    int c4 = (idx & 7) << 2;
    float4 v = *(const float4*)(G + (long)row * lda + kk + c4);
    ushort4 h, l;
    cvt4split(v, h, l);
    int cs = c4 ^ swz8(row);
    *(ushort4*)(&Sh[row * LDP + cs]) = h;
    *(ushort4*)(&Sl[row * LDP + cs]) = l;
  }
}

// ---------------------------------------------------------------------------
// Precast kernel: p -> hi/lo bf16 (memory-bound, once at graph front).
// ---------------------------------------------------------------------------
__global__ __launch_bounds__(256) void k_prep_p(const float* __restrict__ p,
                                                unsigned short* __restrict__ ph,
                                                unsigned short* __restrict__ pl) {
  const long n4 = (long)128 * Sq * Hq / 4;
  const long stride = (long)gridDim.x * blockDim.x;
  for (long i = (long)blockIdx.x * blockDim.x + threadIdx.x; i < n4; i += stride) {
    float4 v = ((const float4*)p)[i];
    ushort4 h, l;
    cvt4split(v, h, l);
    ((ushort4*)ph)[i] = h;
    ((ushort4*)pl)[i] = l;
  }
}

// ---------------------------------------------------------------------------
// Tiled MFMA GEMM core: C[128x128] = A[128xK] * B^T. B is [N,K] row-major.
// A: fp32 (VALU convert) or bf16 (DMA). B: fp32 (VALU convert) or bf16 (DMA).
// ---------------------------------------------------------------------------
template <bool A_F32, bool B_F32>
__device__ __forceinline__ void gemm_tile(const void* __restrict__ Av, int lda,
                                          const void* __restrict__ Bv, int ldb, int K,
                                          f32x4 acc[4][4]) {
  __shared__ __align__(16) unsigned short As[128 * LDP];
  __shared__ __align__(16) unsigned short Bs[128 * LDP];
  const int tid = threadIdx.x;
  const int lane = tid & 63;
  const int wid = tid >> 6;
  const int wr = (wid >> 1) << 6;
  const int wc = (wid & 1) << 6;
  const int q4 = lane >> 4;
  const int l16 = lane & 15;

#pragma unroll
  for (int mi = 0; mi < 4; ++mi)
#pragma unroll
    for (int ni = 0; ni < 4; ++ni) acc[mi][ni] = (f32x4){0.f, 0.f, 0.f, 0.f};

  for (int kk = 0; kk < K; kk += 32) {
    __syncthreads();
    if constexpr (A_F32)
      stage_f32<128>((const float*)Av, lda, kk, As, tid);
    else
      dma_b16<128>((const unsigned short*)Av, lda, kk, As, tid);
    if constexpr (B_F32)
      stage_f32<128>((const float*)Bv, ldb, kk, Bs, tid);
    else
      dma_b16<128>((const unsigned short*)Bv, ldb, kk, Bs, tid);
    __syncthreads();
    bf16x8 af[4], bfr[4];
#pragma unroll
    for (int mi = 0; mi < 4; ++mi) {
      int rr = wr + mi * 16 + l16;
      af[mi] = *(const bf16x8*)(&As[rr * LDP + ((q4 << 3) ^ swz8(rr))]);
    }
#pragma unroll
    for (int ni = 0; ni < 4; ++ni) {
      int rr = wc + ni * 16 + l16;
      bfr[ni] = *(const bf16x8*)(&Bs[rr * LDP + ((q4 << 3) ^ swz8(rr))]);
    }
#pragma unroll
    for (int mi = 0; mi < 4; ++mi)
#pragma unroll
      for (int ni = 0; ni < 4; ++ni)
        acc[mi][ni] =
            __builtin_amdgcn_mfma_f32_16x16x32_bf16(af[mi], bfr[ni], acc[mi][ni], 0, 0, 0);
  }
}

// Split-precision GEMM core: A precast hi/lo bf16 (DMA); B fp32 split-staged.
__device__ __forceinline__ void gemm_tile_split(const unsigned short* __restrict__ Ahp,
                                                const unsigned short* __restrict__ Alp, int lda,
                                                const float* __restrict__ B, int ldb, int K,
                                                f32x4 acc[4][4]) {
  __shared__ __align__(16) unsigned short Ah[128 * LDP], Al[128 * LDP];
  __shared__ __align__(16) unsigned short Bh[128 * LDP], Bl[128 * LDP];
  const int tid = threadIdx.x;
  const int lane = tid & 63;
  const int wid = tid >> 6;
  const int wr = (wid >> 1) << 6;
  const int wc = (wid & 1) << 6;
  const int q4 = lane >> 4;
  const int l16 = lane & 15;

#pragma unroll
  for (int mi = 0; mi < 4; ++mi)
#pragma unroll
    for (int ni = 0; ni < 4; ++ni) acc[mi][ni] = (f32x4){0.f, 0.f, 0.f, 0.f};

  for (int kk = 0; kk < K; kk += 32) {
    __syncthreads();
    dma_b16<128>(Ahp, lda, kk, Ah, tid);
    dma_b16<128>(Alp, lda, kk, Al, tid);
    stage_f32_split<128>(B, ldb, kk, Bh, Bl, tid);
    __syncthreads();
    bf16x8 ah[4], al[4], bh[4], bl[4];
#pragma unroll
    for (int mi = 0; mi < 4; ++mi) {
      int rr = wr + mi * 16 + l16;
      int co = (q4 << 3) ^ swz8(rr);
      ah[mi] = *(const bf16x8*)(&Ah[rr * LDP + co]);
      al[mi] = *(const bf16x8*)(&Al[rr * LDP + co]);
    }
#pragma unroll
    for (int ni = 0; ni < 4; ++ni) {
      int rr = wc + ni * 16 + l16;
      int co = (q4 << 3) ^ swz8(rr);
      bh[ni] = *(const bf16x8*)(&Bh[rr * LDP + co]);
      bl[ni] = *(const bf16x8*)(&Bl[rr * LDP + co]);
    }
#pragma unroll
    for (int mi = 0; mi < 4; ++mi)
#pragma unroll
      for (int ni = 0; ni < 4; ++ni) {
        acc[mi][ni] =
            __builtin_amdgcn_mfma_f32_16x16x32_bf16(ah[mi], bh[ni], acc[mi][ni], 0, 0, 0);
        acc[mi][ni] =
            __builtin_amdgcn_mfma_f32_16x16x32_bf16(ah[mi], bl[ni], acc[mi][ni], 0, 0, 0);
        acc[mi][ni] =
            __builtin_amdgcn_mfma_f32_16x16x32_bf16(al[mi], bh[ni], acc[mi][ni], 0, 0, 0);
      }
  }
}

// C/D layout (m89-verified): col=lane&15, row=(lane>>4)*4+reg.
#define EPI_BEGIN()                                        \
  const int lane = threadIdx.x & 63;                       \
  const int wid = threadIdx.x >> 6;                        \
  const int wr = (wid >> 1) << 6, wc = (wid & 1) << 6;     \
  const int q4 = lane >> 4, l16 = lane & 15;               \
  _Pragma("unroll") for (int mi = 0; mi < 4; ++mi)         \
      _Pragma("unroll") for (int ni = 0; ni < 4; ++ni)

// ---------------------------------------------------------------------------
// K1: tp = p @ Wt^T + bt  (split precision, stored as hi/lo bf16 pair)
__global__ __launch_bounds__(256) void k_tp(const unsigned short* __restrict__ ph,
                                            const unsigned short* __restrict__ pl,
                                            const float* __restrict__ Wt,
                                            const float* __restrict__ bt,
                                            unsigned short* __restrict__ tph,
                                            unsigned short* __restrict__ tpl) {
  const int bm = blockIdx.x * 128, bn = blockIdx.y * 128;
  f32x4 acc[4][4];
  gemm_tile_split(ph + (long)bm * Hq, pl + (long)bm * Hq, Hq, Wt + (long)bn * Hq, Hq, Hq, acc);
  const bool has_lo = (tpl != nullptr);
  EPI_BEGIN() {
    int col = bn + wc + ni * 16 + l16;
    float bv = bt[col];
#pragma unroll
    for (int r = 0; r < 4; ++r) {
      int row = bm + wr + mi * 16 + q4 * 4 + r;
      float v = acc[mi][ni][r] + bv;
      unsigned short h = f2bf(v);
      tph[(long)row * Hq + col] = h;
      if (has_lo) tpl[(long)row * Hq + col] = f2bf(v - bf2f(h));
    }
  }
}

// K2: pdT[b][h][s] = (p @ Wd^T)[b*256+s][h]  (transposed store; bd added in k_occ)
__global__ __launch_bounds__(256) void k_pd(const unsigned short* __restrict__ ph,
                                            const float* __restrict__ Wd,
                                            unsigned short* __restrict__ pdT) {
  const int bm = blockIdx.x * 128, bn = blockIdx.y * 128;
  f32x4 acc[4][4];
  gemm_tile<false, true>(ph + (long)bm * Hq, Hq, Wd + (long)bn * Hq, Hq, Hq, acc);
  EPI_BEGIN() {
    int col = bn + wc + ni * 16 + l16;          // h index
    int rbase = bm + wr + mi * 16 + (q4 << 2);  // global row = b*256 + s
    int b = rbase >> 8, s0 = rbase & 255;
    ushort4 o;
    o.x = f2bf(acc[mi][ni][0]);
    o.y = f2bf(acc[mi][ni][1]);
    o.z = f2bf(acc[mi][ni][2]);
    o.w = f2bf(acc[mi][ni][3]);
    *(ushort4*)(pdT + ((long)b * Hq + col) * Sq + s0) = o;
  }
}

// ---------------------------------------------------------------------------
// K3 (fused): sm[b,k] = masked_softmax(p[b] @ tp[j]^T)  -> bf16 [384,256,256]
// Split-precision scores: p hi/lo (precast) x tp hi/lo (precomputed).
// Block: 128 rows x 256 cols. 4 waves: 2 row-groups x 2 col-halves.
// XCD-swizzled block order for group-local tp reuse in per-XCD L2.
// ---------------------------------------------------------------------------
__global__ __launch_bounds__(256, 1) void k_attsm(const unsigned short* __restrict__ ph,
                                                  const unsigned short* __restrict__ pl,
                                                  const unsigned short* __restrict__ tph,
                                                  const unsigned short* __restrict__ tpl,
                                                  const int* __restrict__ olen,
                                                  unsigned short* __restrict__ sm) {
  // Bijective XCD swizzle: 768 blocks = 8 XCDs x 96 chunks.
  const int lin = blockIdx.x + 2 * blockIdx.y;
  const int w = (lin & 7) * 96 + (lin >> 3);
  const int batch = w >> 1;
  const int bm = (w & 1) * 128;

  const int b = batch / 3, k = batch % 3;
  const int j = other_of(b, k);
  const int len = olen[j] + 1;  // key length, 1..255
  const int tid = threadIdx.x;
  const int lane = tid & 63;
  const int wid = tid >> 6;
  const int wr = (wid >> 1) << 6;  // 0 or 64
  const int wc = (wid & 1) << 7;   // 0 or 128
  const int half = wid & 1;
  const int q4 = lane >> 4, l16 = lane & 15;
  const bool has_lo = (tpl != nullptr);

  __shared__ __align__(16) unsigned short Ah[128 * LDP], Al[128 * LDP];
  __shared__ __align__(16) unsigned short Bh[256 * LDP], Bl[256 * LDP];
  __shared__ float red[256];  // 128 rows x 2 column-halves

  const unsigned short* Aph = ph + ((long)b * Sq + bm) * Hq;
  const unsigned short* Apl = pl + ((long)b * Sq + bm) * Hq;
  const unsigned short* Bph = tph + (long)j * Sq * Hq;
  const unsigned short* Bpl = has_lo ? tpl + (long)j * Sq * Hq : nullptr;

  f32x4 acc[4][8];
#pragma unroll
  for (int mi = 0; mi < 4; ++mi)
#pragma unroll
    for (int ni = 0; ni < 8; ++ni) acc[mi][ni] = (f32x4){0.f, 0.f, 0.f, 0.f};

  for (int kk = 0; kk < Hq; kk += 32) {
    __syncthreads();
    dma_b16<128>(Aph, Hq, kk, Ah, tid);
    dma_b16<128>(Apl, Hq, kk, Al, tid);
    dma_b16<256>(Bph, Hq, kk, Bh, tid);
    if (has_lo) dma_b16<256>(Bpl, Hq, kk, Bl, tid);
    __syncthreads();
    bf16x8 ah[4], al[4];
#pragma unroll
    for (int mi = 0; mi < 4; ++mi) {
      int rr = wr + mi * 16 + l16;
      int co = (q4 << 3) ^ swz8(rr);
      ah[mi] = *(const bf16x8*)(&Ah[rr * LDP + co]);
      al[mi] = *(const bf16x8*)(&Al[rr * LDP + co]);
    }
#pragma unroll
    for (int ni = 0; ni < 8; ++ni) {
      int rr = wc + ni * 16 + l16;
      int co = (q4 << 3) ^ swz8(rr);
      bf16x8 bh = *(const bf16x8*)(&Bh[rr * LDP + co]);
#pragma unroll
      for (int mi = 0; mi < 4; ++mi) {
        acc[mi][ni] = __builtin_amdgcn_mfma_f32_16x16x32_bf16(ah[mi], bh, acc[mi][ni], 0, 0, 0);
        acc[mi][ni] = __builtin_amdgcn_mfma_f32_16x16x32_bf16(al[mi], bh, acc[mi][ni], 0, 0, 0);
      }
      if (has_lo) {
        bf16x8 bl = *(const bf16x8*)(&Bl[rr * LDP + co]);
#pragma unroll
        for (int mi = 0; mi < 4; ++mi)
          acc[mi][ni] = __builtin_amdgcn_mfma_f32_16x16x32_bf16(ah[mi], bl, acc[mi][ni], 0, 0, 0);
      }
    }
  }

  // ---- reference-faithful masked softmax, numerically stable ----
  bool cm[8];
#pragma unroll
  for (int ni = 0; ni < 8; ++ni) cm[ni] = (wc + ni * 16 + l16) >= len;
#pragma unroll
  for (int mi = 0; mi < 4; ++mi)
#pragma unroll
    for (int ni = 0; ni < 8; ++ni)
      if (cm[ni]) acc[mi][ni] = (f32x4){0.f, 0.f, 0.f, 0.f};  // score*mask

  float rmax[4][4];
#pragma unroll
  for (int mi = 0; mi < 4; ++mi)
#pragma unroll
    for (int r = 0; r < 4; ++r) {
      float m = acc[mi][0][r];
#pragma unroll
      for (int ni = 1; ni < 8; ++ni) m = fmaxf(m, acc[mi][ni][r]);
#pragma unroll
      for (int off = 1; off <= 8; off <<= 1) m = fmaxf(m, __shfl_xor(m, off, 64));
      rmax[mi][r] = m;  // max over this col-half (includes masked zeros)
    }
  if (l16 == 0) {
#pragma unroll
    for (int mi = 0; mi < 4; ++mi)
#pragma unroll
      for (int r = 0; r < 4; ++r) red[(wr + mi * 16 + q4 * 4 + r) * 2 + half] = rmax[mi][r];
  }
  __syncthreads();
#pragma unroll
  for (int mi = 0; mi < 4; ++mi)
#pragma unroll
    for (int r = 0; r < 4; ++r) {
      int row = wr + mi * 16 + q4 * 4 + r;
      rmax[mi][r] = fmaxf(red[row * 2], red[row * 2 + 1]);
    }
  __syncthreads();  // red reads done before reuse

  // su = sum of exp over UNMASKED entries only (stable).
  float rsum[4][4];
#pragma unroll
  for (int mi = 0; mi < 4; ++mi)
#pragma unroll
    for (int r = 0; r < 4; ++r) rsum[mi][r] = 0.f;
#pragma unroll
  for (int mi = 0; mi < 4; ++mi)
#pragma unroll
    for (int ni = 0; ni < 8; ++ni)
#pragma unroll
      for (int r = 0; r < 4; ++r) {
        float e = __expf(acc[mi][ni][r] - rmax[mi][r]);
        acc[mi][ni][r] = e;
        if (!cm[ni]) rsum[mi][r] += e;
      }
#pragma unroll
  for (int mi = 0; mi < 4; ++mi)
#pragma unroll
    for (int r = 0; r < 4; ++r) {
#pragma unroll
      for (int off = 1; off <= 8; off <<= 1) rsum[mi][r] += __shfl_xor(rsum[mi][r], off, 64);
    }
  if (l16 == 0) {
#pragma unroll
    for (int mi = 0; mi < 4; ++mi)
#pragma unroll
      for (int r = 0; r < 4; ++r) red[(wr + mi * 16 + q4 * 4 + r) * 2 + half] = rsum[mi][r];
  }
  __syncthreads();

  const float nm = (float)(Sq - len);
  unsigned short* srow = sm + (long)batch * Sq * Sq;
#pragma unroll
  for (int mi = 0; mi < 4; ++mi)
#pragma unroll
    for (int r = 0; r < 4; ++r) {
      int row = wr + mi * 16 + q4 * 4 + r;
      float su = red[row * 2] + red[row * 2 + 1];  // unmasked sum (>=0)
      float em = __expf(-rmax[mi][r]);             // masked entries' e
      float zs = su + nm * em;                     // full softmax denom
      float fs = 1.f / (su + 1e-13f * zs);         // stable renorm
      unsigned short* o = srow + (long)(bm + row) * Sq + wc + l16;
#pragma unroll
      for (int ni = 0; ni < 8; ++ni)
        o[ni * 16] = f2bf(cm[ni] ? 0.f : acc[mi][ni][r] * fs);
    }
}

// K4: occ[(b,s,k),:] = relu(sm[b,k] @ pd[j] + bd)   rows in (b,s,k) order
// pd consumed via pdT[j][h][s]: B[N=h,K=s] row-major -> DMA staging.
// XCD-swizzled block order for batch-local sm/pdT reuse in per-XCD L2.
__global__ __launch_bounds__(256) void k_occ(const unsigned short* __restrict__ sm,
                                             const unsigned short* __restrict__ pdT,
                                             const float* __restrict__ bd,
                                             unsigned short* __restrict__ occ) {
  // Bijective XCD swizzle: 4608 blocks = 8 XCDs x 576 chunks.
  const int lin = blockIdx.x + 2 * (blockIdx.y + 6 * blockIdx.z);
  const int w = (lin & 7) * 576 + (lin >> 3);
  const int t = w >> 1;
  const int bm = (w & 1) * 128, bn = (t % 6) * 128;
  const int batch = t / 6;

  const int b = batch / 3, k = batch % 3;
  const int j = other_of(b, k);
  f32x4 acc[4][4];
  gemm_tile<false, false>(sm + (long)batch * Sq * Sq + (long)bm * Sq, Sq,
                          pdT + ((long)j * Hq + bn) * Sq, Sq, Sq, acc);
  EPI_BEGIN() {
    int col = bn + wc + ni * 16 + l16;
    float bv = bd[col];
#pragma unroll
    for (int r = 0; r < 4; ++r) {
      int s = bm + wr + mi * 16 + q4 * 4 + r;
      occ[((long)(b * Sq + s) * 3 + k) * Hq + col] = f2bf(fmaxf(acc[mi][ni][r] + bv, 0.f));
    }
  }
}

// K5: oc = occ_flat[32768,2304] @ Wd3^T + bd3  -> bf16
__global__ __launch_bounds__(256) void k_oc(const unsigned short* __restrict__ occ,
                                            const float* __restrict__ Wd3,
                                            const float* __restrict__ bd3,
                                            unsigned short* __restrict__ oc) {
  const int bm = blockIdx.x * 128, bn = blockIdx.y * 128;
  f32x4 acc[4][4];
  gemm_tile<false, true>(occ + (long)bm * 3 * Hq, 3 * Hq, Wd3 + (long)bn * 3 * Hq, 3 * Hq,
                         3 * Hq, acc);
  EPI_BEGIN() {
    int col = bn + wc + ni * 16 + l16;
    float bv = bd3[col];
#pragma unroll
    for (int r = 0; r < 4; ++r) {
      int row = bm + wr + mi * 16 + q4 * 4 + r;
      oc[(long)row * Hq + col] = f2bf(acc[mi][ni][r] + bv);
    }
  }
}

// K6: g1 = oc @ W1^T + b1 + b2  -> bf16
__global__ __launch_bounds__(256) void k_g1(const unsigned short* __restrict__ oc,
                                            const float* __restrict__ W1,
                                            const float* __restrict__ b1,
                                            const float* __restrict__ b2,
                                            unsigned short* __restrict__ g1) {
  const int bm = blockIdx.x * 128, bn = blockIdx.y * 128;
  f32x4 acc[4][4];
  gemm_tile<false, true>(oc + (long)bm * Hq, Hq, W1 + (long)bn * Hq, Hq, Hq, acc);
  EPI_BEGIN() {
    int col = bn + wc + ni * 16 + l16;
    float bv = b1[col] + b2[col];
#pragma unroll
    for (int r = 0; r < 4; ++r) {
      int row = bm + wr + mi * 16 + q4 * 4 + r;
      g1[(long)row * Hq + col] = f2bf(acc[mi][ni][r] + bv);
    }
  }
}

// K7: mid = sigmoid(g1 + p @ W2^T); out = p*mid + oc*(1-mid)  (fp32 out)
__global__ __launch_bounds__(256) void k_out(const float* __restrict__ p,
                                             const float* __restrict__ W2,
                                             const unsigned short* __restrict__ g1,
                                             const unsigned short* __restrict__ oc,
                                             float* __restrict__ out) {
  const int bm = blockIdx.x * 128, bn = blockIdx.y * 128;
  f32x4 acc[4][4];
  gemm_tile<true, true>(p + (long)bm * Hq, Hq, W2 + (long)bn * Hq, Hq, Hq, acc);
  EPI_BEGIN() {
    int col = bn + wc + ni * 16 + l16;
#pragma unroll
    for (int r = 0; r < 4; ++r) {
      int row = bm + wr + mi * 16 + q4 * 4 + r;
      long idx = (long)row * Hq + col;
      float g = acc[mi][ni][r] + bf2f(g1[idx]);
      float mid = 1.f / (1.f + __expf(-g));
      float pv = p[idx];
      float ov = bf2f(oc[idx]);
      out[idx] = pv * mid + ov * (1.f - mid);
    }
  }
}

// ---------------------------------------------------------------------------
extern "C" void kernel_launch(void* const* d_in, const int* in_sizes, int n_in, void* d_out,
                              int out_size, void* d_ws, size_t ws_size, hipStream_t stream) {
  const float* p = (const float*)d_in[0];
  const int* olen = (const int*)d_in[1];
  const float* Wt = (const float*)d_in[2];
  const float* bt = (const float*)d_in[3];
  const float* Wd = (const float*)d_in[4];
  const float* bd = (const float*)d_in[5];
  const float* Wd3 = (const float*)d_in[6];
  const float* bd3 = (const float*)d_in[7];
  const float* W1 = (const float*)d_in[8];
  const float* b1 = (const float*)d_in[9];
  const float* W2 = (const float*)d_in[10];
  const float* b2 = (const float*)d_in[11];
  float* out = (float*)d_out;

  char* ws = (char*)d_ws;
  const long U = 50331648L;  // 48 MiB unit
  unsigned short *tph, *tpl, *ph, *pl, *pdT, *sm, *occ, *oc, *g1;
  if (ws_size >= (size_t)(6 * U)) {
    // 288 MiB layout:
    //   slot0: tph (K1->K3), occ (K4->K5)
    //   slot1: tpl (K1->K3), occ
    //   slot2: pl  (prep->K3), occ
    //   slot3: ph  (prep->K3), oc (K5->K7)
    //   slot4: sm  (K3->K4),  g1 (K6->K7)
    //   slot5: pdT (K2->K4)
    tph = (unsigned short*)(ws + 0 * U);
    tpl = (unsigned short*)(ws + 1 * U);
    pl = (unsigned short*)(ws + 2 * U);
    ph = (unsigned short*)(ws + 3 * U);
    occ = (unsigned short*)(ws + 0 * U);
    oc = (unsigned short*)(ws + 3 * U);
    sm = (unsigned short*)(ws + 4 * U);
    g1 = (unsigned short*)(ws + 4 * U);
    pdT = (unsigned short*)(ws + 5 * U);
  } else {
    // 240 MiB fallback: drop tp_lo (p-split only in k_attsm).
    //   slot0: tph, occ   slot1: ph, occ   slot2: pl, occ
    //   slot3: pdT (K2->K4), oc (K5->K7)   slot4: sm, g1
    tph = (unsigned short*)(ws + 0 * U);
    tpl = nullptr;
    ph = (unsigned short*)(ws + 1 * U);
    pl = (unsigned short*)(ws + 2 * U);
    occ = (unsigned short*)(ws + 0 * U);
    pdT = (unsigned short*)(ws + 3 * U);
    oc = (unsigned short*)(ws + 3 * U);
    sm = (unsigned short*)(ws + 4 * U);
    g1 = (unsigned short*)(ws + 4 * U);
  }

  k_prep_p<<<2048, 256, 0, stream>>>(p, ph, pl);
  k_tp<<<dim3(256, 6), 256, 0, stream>>>(ph, pl, Wt, bt, tph, tpl);
  k_pd<<<dim3(256, 6), 256, 0, stream>>>(ph, Wd, pdT);
  k_attsm<<<dim3(2, 384), 256, 0, stream>>>(ph, pl, tph, tpl, olen, sm);
  k_occ<<<dim3(2, 6, 384), 256, 0, stream>>>(sm, pdT, bd, occ);
  k_oc<<<dim3(256, 6), 256, 0, stream>>>(occ, Wd3, bd3, oc);
  k_g1<<<dim3(256, 6), 256, 0, stream>>>(oc, W1, b1, b2, g1);
  k_out<<<dim3(256, 6), 256, 0, stream>>>(p, W2, g1, oc, out);
}

// Round 5
// 966.544 us; speedup vs baseline: 1.3295x; 1.2032x over previous
//
#include <hip/hip_runtime.h>
#include <hip/hip_bf16.h>

constexpr int Sq = 256;
constexpr int Hq = 768;
constexpr int EW = Hq * Hq;  // one HxH weight matrix, in elements

typedef __attribute__((ext_vector_type(4))) float f32x4;
typedef __attribute__((ext_vector_type(8))) short bf16x8;

__device__ __forceinline__ float bf2f(unsigned short u) {
  unsigned int x = ((unsigned int)u) << 16;
  float f;
  __builtin_memcpy(&f, &x, 4);
  return f;
}
__device__ __forceinline__ unsigned short f2bf(float f) {
  unsigned int x;
  __builtin_memcpy(&x, &f, 4);
  unsigned int lsb = (x >> 16) & 1u;
  x += 0x7fffu + lsb;  // round-to-nearest-even
  return (unsigned short)(x >> 16);
}
__device__ __forceinline__ ushort4 cvt4(float4 v) {
  ushort4 o;
  o.x = f2bf(v.x);
  o.y = f2bf(v.y);
  o.z = f2bf(v.z);
  o.w = f2bf(v.w);
  return o;
}
__device__ __forceinline__ void cvt4split(float4 v, ushort4& h, ushort4& l) {
  h.x = f2bf(v.x);
  l.x = f2bf(v.x - bf2f(h.x));
  h.y = f2bf(v.y);
  l.y = f2bf(v.y - bf2f(h.y));
  h.z = f2bf(v.z);
  l.z = f2bf(v.z - bf2f(h.z));
  h.w = f2bf(v.w);
  l.w = f2bf(v.w - bf2f(h.w));
}

// For option b (within its group of 4), the k-th other option (ascending).
__device__ __forceinline__ int other_of(int b, int k) {
  int i = b & 3;
  int jl = k + (k >= i ? 1 : 0);
  return (b & ~3) + jl;
}

constexpr int LDP = 32;  // LINEAR K-stride (64B rows) — required by global_load_lds

// Row-dependent XOR swizzle (element units, 8-elem granules). Applied to the
// GLOBAL source of DMA staging, to VALU LDS writes, and to fragment reads.
// LDS[row][c] always holds G[row][c ^ swz8(row)]; reads XOR again -> identity.
__device__ __forceinline__ int swz8(int row) { return ((row >> 1) & 3) << 3; }

// Async 16B global -> LDS (DMA). Dest must be wave-uniform base + lane*16B.
__device__ __forceinline__ void gload16(const unsigned short* g, unsigned short* s) {
  __builtin_amdgcn_global_load_lds((const __attribute__((address_space(1))) unsigned int*)g,
                                   (__attribute__((address_space(3))) unsigned int*)s, 16, 0, 0);
}

// Stage [ROWS x 32] bf16 tile -> LDS via DMA, source pre-swizzled.
template <int ROWS>
__device__ __forceinline__ void dma_b16(const unsigned short* __restrict__ G, int lda, int kk,
                                        unsigned short* __restrict__ S, int tid) {
#pragma unroll
  for (int pp = 0; pp < ROWS / 64; ++pp) {
    int idx = tid + pp * 256;
    int row = idx >> 2;
    int c8 = ((idx & 3) << 3) ^ swz8(row);
    gload16(G + (long)row * lda + kk + c8, S + idx * 8);
  }
}

// Stage [ROWS x 32] fp32 tile -> bf16 LDS (single rounding), swizzled write.
template <int ROWS>
__device__ __forceinline__ void stage_f32(const float* __restrict__ G, int lda, int kk,
                                          unsigned short* __restrict__ S, int tid) {
#pragma unroll
  for (int pp = 0; pp < ROWS / 32; ++pp) {
    int idx = tid + pp * 256;
    int row = idx >> 3;
    int c4 = (idx & 7) << 2;
    float4 v = *(const float4*)(G + (long)row * lda + kk + c4);
    *(ushort4*)(&S[row * LDP + (c4 ^ swz8(row))]) = cvt4(v);
  }
}

// Stage [ROWS x 32] fp32 tile -> hi/lo bf16 LDS pair (split), swizzled write.
template <int ROWS>
__device__ __forceinline__ void stage_f32_split(const float* __restrict__ G, int lda, int kk,
                                                unsigned short* __restrict__ Sh,
                                                unsigned short* __restrict__ Sl, int tid) {
#pragma unroll
  for (int pp = 0; pp < ROWS / 32; ++pp) {
    int idx = tid + pp * 256;
    int row = idx >> 3;
    int c4 = (idx & 7) << 2;
    float4 v = *(const float4*)(G + (long)row * lda + kk + c4);
    ushort4 h, l;
    cvt4split(v, h, l);
    int cs = c4 ^ swz8(row);
    *(ushort4*)(&Sh[row * LDP + cs]) = h;
    *(ushort4*)(&Sl[row * LDP + cs]) = l;
  }
}

// ---------------------------------------------------------------------------
// Precast kernels (memory-bound, once at graph front). All outputs workspace.
// ---------------------------------------------------------------------------
__global__ __launch_bounds__(256) void k_prep_p(const float* __restrict__ p,
                                                unsigned short* __restrict__ ph,
                                                unsigned short* __restrict__ pl) {
  const long n4 = (long)128 * Sq * Hq / 4;
  const long stride = (long)gridDim.x * blockDim.x;
  for (long i = (long)blockIdx.x * blockDim.x + threadIdx.x; i < n4; i += stride) {
    float4 v = ((const float4*)p)[i];
    ushort4 h, l;
    cvt4split(v, h, l);
    ((ushort4*)ph)[i] = h;
    ((ushort4*)pl)[i] = l;
  }
}

// wb layout (elements): Wth@0, Wtl@EW, Wdb@2EW, W1b@3EW, W2b@4EW, Wd3b@5EW(+3EW)
__global__ __launch_bounds__(256) void k_prep_w(const float* __restrict__ Wt,
                                                const float* __restrict__ Wd,
                                                const float* __restrict__ Wd3,
                                                const float* __restrict__ W1,
                                                const float* __restrict__ W2,
                                                unsigned short* __restrict__ wb) {
  const int NW4 = EW / 4;
  const int stride = gridDim.x * blockDim.x;
  ushort4* Wth = (ushort4*)(wb);
  ushort4* Wtl = (ushort4*)(wb + EW);
  ushort4* Wdb = (ushort4*)(wb + 2 * EW);
  ushort4* W1b = (ushort4*)(wb + 3 * EW);
  ushort4* W2b = (ushort4*)(wb + 4 * EW);
  ushort4* Wd3b = (ushort4*)(wb + 5 * EW);
  for (int i = blockIdx.x * blockDim.x + threadIdx.x; i < NW4; i += stride) {
    float4 v = ((const float4*)Wt)[i];
    ushort4 h, l;
    cvt4split(v, h, l);
    Wth[i] = h;
    Wtl[i] = l;
    Wdb[i] = cvt4(((const float4*)Wd)[i]);
    W1b[i] = cvt4(((const float4*)W1)[i]);
    W2b[i] = cvt4(((const float4*)W2)[i]);
  }
  for (int i = blockIdx.x * blockDim.x + threadIdx.x; i < 3 * NW4; i += stride)
    Wd3b[i] = cvt4(((const float4*)Wd3)[i]);
}

// ---------------------------------------------------------------------------
// Tiled MFMA GEMM core: C[128x128] = A[128xK] * B^T. B is [N,K] row-major.
// A/B: fp32 (VALU convert, swizzled write) or bf16 (DMA, pre-swizzled source).
// ---------------------------------------------------------------------------
template <bool A_F32, bool B_F32>
__device__ __forceinline__ void gemm_tile(const void* __restrict__ Av, int lda,
                                          const void* __restrict__ Bv, int ldb, int K,
                                          f32x4 acc[4][4]) {
  __shared__ __align__(16) unsigned short As[128 * LDP];
  __shared__ __align__(16) unsigned short Bs[128 * LDP];
  const int tid = threadIdx.x;
  const int lane = tid & 63;
  const int wid = tid >> 6;
  const int wr = (wid >> 1) << 6;
  const int wc = (wid & 1) << 6;
  const int q4 = lane >> 4;
  const int l16 = lane & 15;

#pragma unroll
  for (int mi = 0; mi < 4; ++mi)
#pragma unroll
    for (int ni = 0; ni < 4; ++ni) acc[mi][ni] = (f32x4){0.f, 0.f, 0.f, 0.f};

  for (int kk = 0; kk < K; kk += 32) {
    __syncthreads();
    if constexpr (A_F32)
      stage_f32<128>((const float*)Av, lda, kk, As, tid);
    else
      dma_b16<128>((const unsigned short*)Av, lda, kk, As, tid);
    if constexpr (B_F32)
      stage_f32<128>((const float*)Bv, ldb, kk, Bs, tid);
    else
      dma_b16<128>((const unsigned short*)Bv, ldb, kk, Bs, tid);
    __syncthreads();
    bf16x8 af[4], bfr[4];
#pragma unroll
    for (int mi = 0; mi < 4; ++mi) {
      int rr = wr + mi * 16 + l16;
      af[mi] = *(const bf16x8*)(&As[rr * LDP + ((q4 << 3) ^ swz8(rr))]);
    }
#pragma unroll
    for (int ni = 0; ni < 4; ++ni) {
      int rr = wc + ni * 16 + l16;
      bfr[ni] = *(const bf16x8*)(&Bs[rr * LDP + ((q4 << 3) ^ swz8(rr))]);
    }
#pragma unroll
    for (int mi = 0; mi < 4; ++mi)
#pragma unroll
      for (int ni = 0; ni < 4; ++ni)
        acc[mi][ni] =
            __builtin_amdgcn_mfma_f32_16x16x32_bf16(af[mi], bfr[ni], acc[mi][ni], 0, 0, 0);
  }
}

// Split-precision GEMM core: A precast hi/lo bf16 (DMA); B fp32 split-staged.
__device__ __forceinline__ void gemm_tile_split(const unsigned short* __restrict__ Ahp,
                                                const unsigned short* __restrict__ Alp, int lda,
                                                const float* __restrict__ B, int ldb, int K,
                                                f32x4 acc[4][4]) {
  __shared__ __align__(16) unsigned short Ah[128 * LDP], Al[128 * LDP];
  __shared__ __align__(16) unsigned short Bh[128 * LDP], Bl[128 * LDP];
  const int tid = threadIdx.x;
  const int lane = tid & 63;
  const int wid = tid >> 6;
  const int wr = (wid >> 1) << 6;
  const int wc = (wid & 1) << 6;
  const int q4 = lane >> 4;
  const int l16 = lane & 15;

#pragma unroll
  for (int mi = 0; mi < 4; ++mi)
#pragma unroll
    for (int ni = 0; ni < 4; ++ni) acc[mi][ni] = (f32x4){0.f, 0.f, 0.f, 0.f};

  for (int kk = 0; kk < K; kk += 32) {
    __syncthreads();
    dma_b16<128>(Ahp, lda, kk, Ah, tid);
    dma_b16<128>(Alp, lda, kk, Al, tid);
    stage_f32_split<128>(B, ldb, kk, Bh, Bl, tid);
    __syncthreads();
    bf16x8 ah[4], al[4], bh[4], bl[4];
#pragma unroll
    for (int mi = 0; mi < 4; ++mi) {
      int rr = wr + mi * 16 + l16;
      int co = (q4 << 3) ^ swz8(rr);
      ah[mi] = *(const bf16x8*)(&Ah[rr * LDP + co]);
      al[mi] = *(const bf16x8*)(&Al[rr * LDP + co]);
    }
#pragma unroll
    for (int ni = 0; ni < 4; ++ni) {
      int rr = wc + ni * 16 + l16;
      int co = (q4 << 3) ^ swz8(rr);
      bh[ni] = *(const bf16x8*)(&Bh[rr * LDP + co]);
      bl[ni] = *(const bf16x8*)(&Bl[rr * LDP + co]);
    }
#pragma unroll
    for (int mi = 0; mi < 4; ++mi)
#pragma unroll
      for (int ni = 0; ni < 4; ++ni) {
        acc[mi][ni] =
            __builtin_amdgcn_mfma_f32_16x16x32_bf16(ah[mi], bh[ni], acc[mi][ni], 0, 0, 0);
        acc[mi][ni] =
            __builtin_amdgcn_mfma_f32_16x16x32_bf16(ah[mi], bl[ni], acc[mi][ni], 0, 0, 0);
        acc[mi][ni] =
            __builtin_amdgcn_mfma_f32_16x16x32_bf16(al[mi], bh[ni], acc[mi][ni], 0, 0, 0);
      }
  }
}

// Split-precision GEMM core: A and B both precast hi/lo bf16 (all DMA).
__device__ __forceinline__ void gemm_tile_split_b16(const unsigned short* __restrict__ Ahp,
                                                    const unsigned short* __restrict__ Alp, int lda,
                                                    const unsigned short* __restrict__ Bhp,
                                                    const unsigned short* __restrict__ Blp, int ldb,
                                                    int K, f32x4 acc[4][4]) {
  __shared__ __align__(16) unsigned short Ah[128 * LDP], Al[128 * LDP];
  __shared__ __align__(16) unsigned short Bh[128 * LDP], Bl[128 * LDP];
  const int tid = threadIdx.x;
  const int lane = tid & 63;
  const int wid = tid >> 6;
  const int wr = (wid >> 1) << 6;
  const int wc = (wid & 1) << 6;
  const int q4 = lane >> 4;
  const int l16 = lane & 15;

#pragma unroll
  for (int mi = 0; mi < 4; ++mi)
#pragma unroll
    for (int ni = 0; ni < 4; ++ni) acc[mi][ni] = (f32x4){0.f, 0.f, 0.f, 0.f};

  for (int kk = 0; kk < K; kk += 32) {
    __syncthreads();
    dma_b16<128>(Ahp, lda, kk, Ah, tid);
    dma_b16<128>(Alp, lda, kk, Al, tid);
    dma_b16<128>(Bhp, ldb, kk, Bh, tid);
    dma_b16<128>(Blp, ldb, kk, Bl, tid);
    __syncthreads();
    bf16x8 ah[4], al[4], bh[4], bl[4];
#pragma unroll
    for (int mi = 0; mi < 4; ++mi) {
      int rr = wr + mi * 16 + l16;
      int co = (q4 << 3) ^ swz8(rr);
      ah[mi] = *(const bf16x8*)(&Ah[rr * LDP + co]);
      al[mi] = *(const bf16x8*)(&Al[rr * LDP + co]);
    }
#pragma unroll
    for (int ni = 0; ni < 4; ++ni) {
      int rr = wc + ni * 16 + l16;
      int co = (q4 << 3) ^ swz8(rr);
      bh[ni] = *(const bf16x8*)(&Bh[rr * LDP + co]);
      bl[ni] = *(const bf16x8*)(&Bl[rr * LDP + co]);
    }
#pragma unroll
    for (int mi = 0; mi < 4; ++mi)
#pragma unroll
      for (int ni = 0; ni < 4; ++ni) {
        acc[mi][ni] =
            __builtin_amdgcn_mfma_f32_16x16x32_bf16(ah[mi], bh[ni], acc[mi][ni], 0, 0, 0);
        acc[mi][ni] =
            __builtin_amdgcn_mfma_f32_16x16x32_bf16(ah[mi], bl[ni], acc[mi][ni], 0, 0, 0);
        acc[mi][ni] =
            __builtin_amdgcn_mfma_f32_16x16x32_bf16(al[mi], bh[ni], acc[mi][ni], 0, 0, 0);
      }
  }
}

// C/D layout (m89-verified): col=lane&15, row=(lane>>4)*4+reg.
#define EPI_BEGIN()                                        \
  const int lane = threadIdx.x & 63;                       \
  const int wid = threadIdx.x >> 6;                        \
  const int wr = (wid >> 1) << 6, wc = (wid & 1) << 6;     \
  const int q4 = lane >> 4, l16 = lane & 15;               \
  _Pragma("unroll") for (int mi = 0; mi < 4; ++mi)         \
      _Pragma("unroll") for (int ni = 0; ni < 4; ++ni)

// ---------------------------------------------------------------------------
// K1: tp = p @ Wt^T + bt  (split precision, stored as hi/lo bf16 pair)
template <bool WF32>
__global__ __launch_bounds__(256) void k_tp(const unsigned short* __restrict__ ph,
                                            const unsigned short* __restrict__ pl,
                                            const void* __restrict__ Wh,
                                            const void* __restrict__ Wl,
                                            const float* __restrict__ bt,
                                            unsigned short* __restrict__ tph,
                                            unsigned short* __restrict__ tpl) {
  const int bm = blockIdx.x * 128, bn = blockIdx.y * 128;
  f32x4 acc[4][4];
  if constexpr (WF32)
    gemm_tile_split(ph + (long)bm * Hq, pl + (long)bm * Hq, Hq,
                    (const float*)Wh + (long)bn * Hq, Hq, Hq, acc);
  else
    gemm_tile_split_b16(ph + (long)bm * Hq, pl + (long)bm * Hq, Hq,
                        (const unsigned short*)Wh + (long)bn * Hq,
                        (const unsigned short*)Wl + (long)bn * Hq, Hq, Hq, acc);
  const bool has_lo = (tpl != nullptr);
  EPI_BEGIN() {
    int col = bn + wc + ni * 16 + l16;
    float bv = bt[col];
#pragma unroll
    for (int r = 0; r < 4; ++r) {
      int row = bm + wr + mi * 16 + q4 * 4 + r;
      float v = acc[mi][ni][r] + bv;
      unsigned short h = f2bf(v);
      tph[(long)row * Hq + col] = h;
      if (has_lo) tpl[(long)row * Hq + col] = f2bf(v - bf2f(h));
    }
  }
}

// K2: pdT[b][h][s] = (p @ Wd^T)[b*256+s][h]  (transposed store; bd added in k_occ)
template <bool WF32>
__global__ __launch_bounds__(256) void k_pd(const unsigned short* __restrict__ ph,
                                            const void* __restrict__ Wd,
                                            unsigned short* __restrict__ pdT) {
  const int bm = blockIdx.x * 128, bn = blockIdx.y * 128;
  f32x4 acc[4][4];
  if constexpr (WF32)
    gemm_tile<false, true>(ph + (long)bm * Hq, Hq, (const float*)Wd + (long)bn * Hq, Hq, Hq, acc);
  else
    gemm_tile<false, false>(ph + (long)bm * Hq, Hq, (const unsigned short*)Wd + (long)bn * Hq,
                            Hq, Hq, acc);
  EPI_BEGIN() {
    int col = bn + wc + ni * 16 + l16;          // h index
    int rbase = bm + wr + mi * 16 + (q4 << 2);  // global row = b*256 + s
    int b = rbase >> 8, s0 = rbase & 255;
    ushort4 o;
    o.x = f2bf(acc[mi][ni][0]);
    o.y = f2bf(acc[mi][ni][1]);
    o.z = f2bf(acc[mi][ni][2]);
    o.w = f2bf(acc[mi][ni][3]);
    *(ushort4*)(pdT + ((long)b * Hq + col) * Sq + s0) = o;
  }
}

// ---------------------------------------------------------------------------
// K3 (fused): sm[b,k] = masked_softmax(p[b] @ tp[j]^T)  -> bf16 [384,256,256]
// Split-precision scores: p hi/lo (precast) x tp hi/lo (precomputed).
// Block: 128 rows x 256 cols. 4 waves: 2 row-groups x 2 col-halves.
// XCD-swizzled block order for group-local tp reuse in per-XCD L2.
// ---------------------------------------------------------------------------
__global__ __launch_bounds__(256, 1) void k_attsm(const unsigned short* __restrict__ ph,
                                                  const unsigned short* __restrict__ pl,
                                                  const unsigned short* __restrict__ tph,
                                                  const unsigned short* __restrict__ tpl,
                                                  const int* __restrict__ olen,
                                                  unsigned short* __restrict__ sm) {
  // Bijective XCD swizzle: 768 blocks = 8 XCDs x 96 chunks.
  const int lin = blockIdx.x + 2 * blockIdx.y;
  const int w = (lin & 7) * 96 + (lin >> 3);
  const int batch = w >> 1;
  const int bm = (w & 1) * 128;

  const int b = batch / 3, k = batch % 3;
  const int j = other_of(b, k);
  const int len = olen[j] + 1;  // key length, 1..255
  const int tid = threadIdx.x;
  const int lane = tid & 63;
  const int wid = tid >> 6;
  const int wr = (wid >> 1) << 6;  // 0 or 64
  const int wc = (wid & 1) << 7;   // 0 or 128
  const int half = wid & 1;
  const int q4 = lane >> 4, l16 = lane & 15;
  const bool has_lo = (tpl != nullptr);

  __shared__ __align__(16) unsigned short Ah[128 * LDP], Al[128 * LDP];
  __shared__ __align__(16) unsigned short Bh[256 * LDP], Bl[256 * LDP];
  __shared__ float red[256];  // 128 rows x 2 column-halves

  const unsigned short* Aph = ph + ((long)b * Sq + bm) * Hq;
  const unsigned short* Apl = pl + ((long)b * Sq + bm) * Hq;
  const unsigned short* Bph = tph + (long)j * Sq * Hq;
  const unsigned short* Bpl = has_lo ? tpl + (long)j * Sq * Hq : nullptr;

  f32x4 acc[4][8];
#pragma unroll
  for (int mi = 0; mi < 4; ++mi)
#pragma unroll
    for (int ni = 0; ni < 8; ++ni) acc[mi][ni] = (f32x4){0.f, 0.f, 0.f, 0.f};

  for (int kk = 0; kk < Hq; kk += 32) {
    __syncthreads();
    dma_b16<128>(Aph, Hq, kk, Ah, tid);
    dma_b16<128>(Apl, Hq, kk, Al, tid);
    dma_b16<256>(Bph, Hq, kk, Bh, tid);
    if (has_lo) dma_b16<256>(Bpl, Hq, kk, Bl, tid);
    __syncthreads();
    bf16x8 ah[4], al[4];
#pragma unroll
    for (int mi = 0; mi < 4; ++mi) {
      int rr = wr + mi * 16 + l16;
      int co = (q4 << 3) ^ swz8(rr);
      ah[mi] = *(const bf16x8*)(&Ah[rr * LDP + co]);
      al[mi] = *(const bf16x8*)(&Al[rr * LDP + co]);
    }
#pragma unroll
    for (int ni = 0; ni < 8; ++ni) {
      int rr = wc + ni * 16 + l16;
      int co = (q4 << 3) ^ swz8(rr);
      bf16x8 bh = *(const bf16x8*)(&Bh[rr * LDP + co]);
#pragma unroll
      for (int mi = 0; mi < 4; ++mi) {
        acc[mi][ni] = __builtin_amdgcn_mfma_f32_16x16x32_bf16(ah[mi], bh, acc[mi][ni], 0, 0, 0);
        acc[mi][ni] = __builtin_amdgcn_mfma_f32_16x16x32_bf16(al[mi], bh, acc[mi][ni], 0, 0, 0);
      }
      if (has_lo) {
        bf16x8 bl = *(const bf16x8*)(&Bl[rr * LDP + co]);
#pragma unroll
        for (int mi = 0; mi < 4; ++mi)
          acc[mi][ni] = __builtin_amdgcn_mfma_f32_16x16x32_bf16(ah[mi], bl, acc[mi][ni], 0, 0, 0);
      }
    }
  }

  // ---- reference-faithful masked softmax, numerically stable ----
  bool cm[8];
#pragma unroll
  for (int ni = 0; ni < 8; ++ni) cm[ni] = (wc + ni * 16 + l16) >= len;
#pragma unroll
  for (int mi = 0; mi < 4; ++mi)
#pragma unroll
    for (int ni = 0; ni < 8; ++ni)
      if (cm[ni]) acc[mi][ni] = (f32x4){0.f, 0.f, 0.f, 0.f};  // score*mask

  float rmax[4][4];
#pragma unroll
  for (int mi = 0; mi < 4; ++mi)
#pragma unroll
    for (int r = 0; r < 4; ++r) {
      float m = acc[mi][0][r];
#pragma unroll
      for (int ni = 1; ni < 8; ++ni) m = fmaxf(m, acc[mi][ni][r]);
#pragma unroll
      for (int off = 1; off <= 8; off <<= 1) m = fmaxf(m, __shfl_xor(m, off, 64));
      rmax[mi][r] = m;  // max over this col-half (includes masked zeros)
    }
  if (l16 == 0) {
#pragma unroll
    for (int mi = 0; mi < 4; ++mi)
#pragma unroll
      for (int r = 0; r < 4; ++r) red[(wr + mi * 16 + q4 * 4 + r) * 2 + half] = rmax[mi][r];
  }
  __syncthreads();
#pragma unroll
  for (int mi = 0; mi < 4; ++mi)
#pragma unroll
    for (int r = 0; r < 4; ++r) {
      int row = wr + mi * 16 + q4 * 4 + r;
      rmax[mi][r] = fmaxf(red[row * 2], red[row * 2 + 1]);
    }
  __syncthreads();  // red reads done before reuse

  // su = sum of exp over UNMASKED entries only (stable).
  float rsum[4][4];
#pragma unroll
  for (int mi = 0; mi < 4; ++mi)
#pragma unroll
    for (int r = 0; r < 4; ++r) rsum[mi][r] = 0.f;
#pragma unroll
  for (int mi = 0; mi < 4; ++mi)
#pragma unroll
    for (int ni = 0; ni < 8; ++ni)
#pragma unroll
      for (int r = 0; r < 4; ++r) {
        float e = __expf(acc[mi][ni][r] - rmax[mi][r]);
        acc[mi][ni][r] = e;
        if (!cm[ni]) rsum[mi][r] += e;
      }
#pragma unroll
  for (int mi = 0; mi < 4; ++mi)
#pragma unroll
    for (int r = 0; r < 4; ++r) {
#pragma unroll
      for (int off = 1; off <= 8; off <<= 1) rsum[mi][r] += __shfl_xor(rsum[mi][r], off, 64);
    }
  if (l16 == 0) {
#pragma unroll
    for (int mi = 0; mi < 4; ++mi)
#pragma unroll
      for (int r = 0; r < 4; ++r) red[(wr + mi * 16 + q4 * 4 + r) * 2 + half] = rsum[mi][r];
  }
  __syncthreads();

  const float nm = (float)(Sq - len);
  unsigned short* srow = sm + (long)batch * Sq * Sq;
#pragma unroll
  for (int mi = 0; mi < 4; ++mi)
#pragma unroll
    for (int r = 0; r < 4; ++r) {
      int row = wr + mi * 16 + q4 * 4 + r;
      float su = red[row * 2] + red[row * 2 + 1];  // unmasked sum (>=0)
      float em = __expf(-rmax[mi][r]);             // masked entries' e
      float zs = su + nm * em;                     // full softmax denom
      float fs = 1.f / (su + 1e-13f * zs);         // stable renorm
      unsigned short* o = srow + (long)(bm + row) * Sq + wc + l16;
#pragma unroll
      for (int ni = 0; ni < 8; ++ni)
        o[ni * 16] = f2bf(cm[ni] ? 0.f : acc[mi][ni][r] * fs);
    }
}

// K4: occ[(b,s,k),:] = relu(sm[b,k] @ pd[j] + bd)   rows in (b,s,k) order
// pd consumed via pdT[j][h][s]: B[N=h,K=s] row-major -> DMA staging.
// XCD-swizzled block order for batch-local sm/pdT reuse in per-XCD L2.
__global__ __launch_bounds__(256) void k_occ(const unsigned short* __restrict__ sm,
                                             const unsigned short* __restrict__ pdT,
                                             const float* __restrict__ bd,
                                             unsigned short* __restrict__ occ) {
  // Bijective XCD swizzle: 4608 blocks = 8 XCDs x 576 chunks.
  const int lin = blockIdx.x + 2 * (blockIdx.y + 6 * blockIdx.z);
  const int w = (lin & 7) * 576 + (lin >> 3);
  const int t = w >> 1;
  const int bm = (w & 1) * 128, bn = (t % 6) * 128;
  const int batch = t / 6;

  const int b = batch / 3, k = batch % 3;
  const int j = other_of(b, k);
  f32x4 acc[4][4];
  gemm_tile<false, false>(sm + (long)batch * Sq * Sq + (long)bm * Sq, Sq,
                          pdT + ((long)j * Hq + bn) * Sq, Sq, Sq, acc);
  EPI_BEGIN() {
    int col = bn + wc + ni * 16 + l16;
    float bv = bd[col];
#pragma unroll
    for (int r = 0; r < 4; ++r) {
      int s = bm + wr + mi * 16 + q4 * 4 + r;
      occ[((long)(b * Sq + s) * 3 + k) * Hq + col] = f2bf(fmaxf(acc[mi][ni][r] + bv, 0.f));
    }
  }
}

// K5: oc = occ_flat[32768,2304] @ Wd3^T + bd3  -> bf16
template <bool WF32>
__global__ __launch_bounds__(256) void k_oc(const unsigned short* __restrict__ occ,
                                            const void* __restrict__ Wd3,
                                            const float* __restrict__ bd3,
                                            unsigned short* __restrict__ oc) {
  const int bm = blockIdx.x * 128, bn = blockIdx.y * 128;
  f32x4 acc[4][4];
  if constexpr (WF32)
    gemm_tile<false, true>(occ + (long)bm * 3 * Hq, 3 * Hq,
                           (const float*)Wd3 + (long)bn * 3 * Hq, 3 * Hq, 3 * Hq, acc);
  else
    gemm_tile<false, false>(occ + (long)bm * 3 * Hq, 3 * Hq,
                            (const unsigned short*)Wd3 + (long)bn * 3 * Hq, 3 * Hq, 3 * Hq, acc);
  EPI_BEGIN() {
    int col = bn + wc + ni * 16 + l16;
    float bv = bd3[col];
#pragma unroll
    for (int r = 0; r < 4; ++r) {
      int row = bm + wr + mi * 16 + q4 * 4 + r;
      oc[(long)row * Hq + col] = f2bf(acc[mi][ni][r] + bv);
    }
  }
}

// K6: g1 = oc @ W1^T + b1 + b2  -> bf16
template <bool WF32>
__global__ __launch_bounds__(256) void k_g1(const unsigned short* __restrict__ oc,
                                            const void* __restrict__ W1,
                                            const float* __restrict__ b1,
                                            const float* __restrict__ b2,
                                            unsigned short* __restrict__ g1) {
  const int bm = blockIdx.x * 128, bn = blockIdx.y * 128;
  f32x4 acc[4][4];
  if constexpr (WF32)
    gemm_tile<false, true>(oc + (long)bm * Hq, Hq, (const float*)W1 + (long)bn * Hq, Hq, Hq, acc);
  else
    gemm_tile<false, false>(oc + (long)bm * Hq, Hq, (const unsigned short*)W1 + (long)bn * Hq,
                            Hq, Hq, acc);
  EPI_BEGIN() {
    int col = bn + wc + ni * 16 + l16;
    float bv = b1[col] + b2[col];
#pragma unroll
    for (int r = 0; r < 4; ++r) {
      int row = bm + wr + mi * 16 + q4 * 4 + r;
      g1[(long)row * Hq + col] = f2bf(acc[mi][ni][r] + bv);
    }
  }
}

// K7: mid = sigmoid(g1 + p @ W2^T); out = p*mid + oc*(1-mid)  (fp32 out)
template <bool WF32>
__global__ __launch_bounds__(256) void k_out(const float* __restrict__ p,
                                             const void* __restrict__ W2,
                                             const unsigned short* __restrict__ g1,
                                             const unsigned short* __restrict__ oc,
                                             float* __restrict__ out) {
  const int bm = blockIdx.x * 128, bn = blockIdx.y * 128;
  f32x4 acc[4][4];
  if constexpr (WF32)
    gemm_tile<true, true>(p + (long)bm * Hq, Hq, (const float*)W2 + (long)bn * Hq, Hq, Hq, acc);
  else
    gemm_tile<true, false>(p + (long)bm * Hq, Hq, (const unsigned short*)W2 + (long)bn * Hq,
                           Hq, Hq, acc);
  EPI_BEGIN() {
    int col = bn + wc + ni * 16 + l16;
#pragma unroll
    for (int r = 0; r < 4; ++r) {
      int row = bm + wr + mi * 16 + q4 * 4 + r;
      long idx = (long)row * Hq + col;
      float g = acc[mi][ni][r] + bf2f(g1[idx]);
      float mid = 1.f / (1.f + __expf(-g));
      float pv = p[idx];
      float ov = bf2f(oc[idx]);
      out[idx] = pv * mid + ov * (1.f - mid);
    }
  }
}

// ---------------------------------------------------------------------------
extern "C" void kernel_launch(void* const* d_in, const int* in_sizes, int n_in, void* d_out,
                              int out_size, void* d_ws, size_t ws_size, hipStream_t stream) {
  const float* p = (const float*)d_in[0];
  const int* olen = (const int*)d_in[1];
  const float* Wt = (const float*)d_in[2];
  const float* bt = (const float*)d_in[3];
  const float* Wd = (const float*)d_in[4];
  const float* bd = (const float*)d_in[5];
  const float* Wd3 = (const float*)d_in[6];
  const float* bd3 = (const float*)d_in[7];
  const float* W1 = (const float*)d_in[8];
  const float* b1 = (const float*)d_in[9];
  const float* W2 = (const float*)d_in[10];
  const float* b2 = (const float*)d_in[11];
  float* out = (float*)d_out;

  char* ws = (char*)d_ws;
  const long U = 50331648L;   // 48 MiB unit
  const long WB = 9437184L;   // 9 MiB precast-weight block

  if (ws_size >= (size_t)(WB + 5 * U)) {
    // 249 MiB layout (byte offsets, MiB):
    //   wb   0..9    (prep_w -> K7)          precast weights
    //   ph   9..57   (prep_p -> k_pd)
    //   pl   57..105 (prep_p -> k_attsm)
    //   tph  105..153 (k_tp -> k_attsm)
    //   tpl  153..201 (k_tp -> k_attsm)
    //   sm   201..249 (k_attsm -> k_occ)
    //   pdT  153..201 (k_pd -> k_occ)        [k_pd runs AFTER k_attsm]
    //   occ  9..153  (k_occ -> k_oc)         [ph,pl,tph dead by then]
    //   oc   153..201 (k_oc -> k_out)        [pdT dead]
    //   g1   201..249 (k_g1 -> k_out)        [sm dead]
    unsigned short* wb = (unsigned short*)(ws);
    unsigned short* ph = (unsigned short*)(ws + WB);
    unsigned short* pl = (unsigned short*)(ws + WB + 1 * U);
    unsigned short* tph = (unsigned short*)(ws + WB + 2 * U);
    unsigned short* tpl = (unsigned short*)(ws + WB + 3 * U);
    unsigned short* sm = (unsigned short*)(ws + WB + 4 * U);
    unsigned short* pdT = (unsigned short*)(ws + WB + 3 * U);
    unsigned short* occ = (unsigned short*)(ws + WB);
    unsigned short* oc = (unsigned short*)(ws + WB + 3 * U);
    unsigned short* g1 = (unsigned short*)(ws + WB + 4 * U);

    k_prep_p<<<2048, 256, 0, stream>>>(p, ph, pl);
    k_prep_w<<<512, 256, 0, stream>>>(Wt, Wd, Wd3, W1, W2, wb);
    k_tp<false><<<dim3(256, 6), 256, 0, stream>>>(ph, pl, wb, wb + EW, bt, tph, tpl);
    k_attsm<<<dim3(2, 384), 256, 0, stream>>>(ph, pl, tph, tpl, olen, sm);
    k_pd<false><<<dim3(256, 6), 256, 0, stream>>>(ph, wb + 2 * EW, pdT);
    k_occ<<<dim3(2, 6, 384), 256, 0, stream>>>(sm, pdT, bd, occ);
    k_oc<false><<<dim3(256, 6), 256, 0, stream>>>(occ, wb + 5 * EW, bd3, oc);
    k_g1<false><<<dim3(256, 6), 256, 0, stream>>>(oc, wb + 3 * EW, b1, b2, g1);
    k_out<false><<<dim3(256, 6), 256, 0, stream>>>(p, wb + 4 * EW, g1, oc, out);
  } else {
    // 240 MiB fallback (Round-4 proven): drop tp_lo, fp32 weights staged on the fly.
    //   slot0: tph, occ   slot1: ph, occ   slot2: pl, occ
    //   slot3: pdT (K2->K4), oc (K5->K7)   slot4: sm, g1
    unsigned short* tph = (unsigned short*)(ws + 0 * U);
    unsigned short* tpl = nullptr;
    unsigned short* ph = (unsigned short*)(ws + 1 * U);
    unsigned short* pl = (unsigned short*)(ws + 2 * U);
    unsigned short* occ = (unsigned short*)(ws + 0 * U);
    unsigned short* pdT = (unsigned short*)(ws + 3 * U);
    unsigned short* oc = (unsigned short*)(ws + 3 * U);
    unsigned short* sm = (unsigned short*)(ws + 4 * U);
    unsigned short* g1 = (unsigned short*)(ws + 4 * U);

    k_prep_p<<<2048, 256, 0, stream>>>(p, ph, pl);
    k_tp<true><<<dim3(256, 6), 256, 0, stream>>>(ph, pl, Wt, nullptr, bt, tph, tpl);
    k_pd<true><<<dim3(256, 6), 256, 0, stream>>>(ph, Wd, pdT);
    k_attsm<<<dim3(2, 384), 256, 0, stream>>>(ph, pl, tph, tpl, olen, sm);
    k_occ<<<dim3(2, 6, 384), 256, 0, stream>>>(sm, pdT, bd, occ);
    k_oc<true><<<dim3(256, 6), 256, 0, stream>>>(occ, Wd3, bd3, oc);
    k_g1<true><<<dim3(256, 6), 256, 0, stream>>>(oc, W1, b1, b2, g1);
    k_out<true><<<dim3(256, 6), 256, 0, stream>>>(p, W2, g1, oc, out);
  }
}

// Round 6
// 937.719 us; speedup vs baseline: 1.3703x; 1.0307x over previous
//
#include <hip/hip_runtime.h>
#include <hip/hip_bf16.h>

constexpr int Sq = 256;
constexpr int Hq = 768;
constexpr int EW = Hq * Hq;  // one HxH weight matrix, in elements

typedef __attribute__((ext_vector_type(4))) float f32x4;
typedef __attribute__((ext_vector_type(8))) short bf16x8;

__device__ __forceinline__ float bf2f(unsigned short u) {
  unsigned int x = ((unsigned int)u) << 16;
  float f;
  __builtin_memcpy(&f, &x, 4);
  return f;
}
__device__ __forceinline__ unsigned short f2bf(float f) {
  unsigned int x;
  __builtin_memcpy(&x, &f, 4);
  unsigned int lsb = (x >> 16) & 1u;
  x += 0x7fffu + lsb;  // round-to-nearest-even
  return (unsigned short)(x >> 16);
}
__device__ __forceinline__ ushort4 cvt4(float4 v) {
  ushort4 o;
  o.x = f2bf(v.x);
  o.y = f2bf(v.y);
  o.z = f2bf(v.z);
  o.w = f2bf(v.w);
  return o;
}
__device__ __forceinline__ void cvt4split(float4 v, ushort4& h, ushort4& l) {
  h.x = f2bf(v.x);
  l.x = f2bf(v.x - bf2f(h.x));
  h.y = f2bf(v.y);
  l.y = f2bf(v.y - bf2f(h.y));
  h.z = f2bf(v.z);
  l.z = f2bf(v.z - bf2f(h.z));
  h.w = f2bf(v.w);
  l.w = f2bf(v.w - bf2f(h.w));
}

// For option b (within its group of 4), the k-th other option (ascending).
__device__ __forceinline__ int other_of(int b, int k) {
  int i = b & 3;
  int jl = k + (k >= i ? 1 : 0);
  return (b & ~3) + jl;
}

constexpr int LDP = 32;  // LINEAR K-stride (64B rows) — required by global_load_lds

// Row-dependent XOR swizzle (element units, 8-elem granules). Applied to the
// GLOBAL source of DMA staging, to VALU LDS writes, and to fragment reads.
// LDS[row][c] always holds G[row][c ^ swz8(row)]; reads XOR again -> identity.
__device__ __forceinline__ int swz8(int row) { return ((row >> 1) & 3) << 3; }

// Async 16B global -> LDS (DMA). Dest must be wave-uniform base + lane*16B.
__device__ __forceinline__ void gload16(const unsigned short* g, unsigned short* s) {
  __builtin_amdgcn_global_load_lds((const __attribute__((address_space(1))) unsigned int*)g,
                                   (__attribute__((address_space(3))) unsigned int*)s, 16, 0, 0);
}

// Stage [ROWS x 32] bf16 tile -> LDS via DMA, source pre-swizzled.
template <int ROWS>
__device__ __forceinline__ void dma_b16(const unsigned short* __restrict__ G, int lda, int kk,
                                        unsigned short* __restrict__ S, int tid) {
#pragma unroll
  for (int pp = 0; pp < ROWS / 64; ++pp) {
    int idx = tid + pp * 256;
    int row = idx >> 2;
    int c8 = ((idx & 3) << 3) ^ swz8(row);
    gload16(G + (long)row * lda + kk + c8, S + idx * 8);
  }
}

// Stage [ROWS x 32] fp32 tile -> bf16 LDS (single rounding), swizzled write.
template <int ROWS>
__device__ __forceinline__ void stage_f32(const float* __restrict__ G, int lda, int kk,
                                          unsigned short* __restrict__ S, int tid) {
#pragma unroll
  for (int pp = 0; pp < ROWS / 32; ++pp) {
    int idx = tid + pp * 256;
    int row = idx >> 3;
    int c4 = (idx & 7) << 2;
    float4 v = *(const float4*)(G + (long)row * lda + kk + c4);
    *(ushort4*)(&S[row * LDP + (c4 ^ swz8(row))]) = cvt4(v);
  }
}

// Stage [ROWS x 32] fp32 tile -> hi/lo bf16 LDS pair (split), swizzled write.
template <int ROWS>
__device__ __forceinline__ void stage_f32_split(const float* __restrict__ G, int lda, int kk,
                                                unsigned short* __restrict__ Sh,
                                                unsigned short* __restrict__ Sl, int tid) {
#pragma unroll
  for (int pp = 0; pp < ROWS / 32; ++pp) {
    int idx = tid + pp * 256;
    int row = idx >> 3;
    int c4 = (idx & 7) << 2;
    float4 v = *(const float4*)(G + (long)row * lda + kk + c4);
    ushort4 h, l;
    cvt4split(v, h, l);
    int cs = c4 ^ swz8(row);
    *(ushort4*)(&Sh[row * LDP + cs]) = h;
    *(ushort4*)(&Sl[row * LDP + cs]) = l;
  }
}

// ---------------------------------------------------------------------------
// Precast kernels (memory-bound, once at graph front). All outputs workspace.
// ---------------------------------------------------------------------------
__global__ __launch_bounds__(256) void k_prep_p(const float* __restrict__ p,
                                                unsigned short* __restrict__ ph,
                                                unsigned short* __restrict__ pl) {
  const long n4 = (long)128 * Sq * Hq / 4;
  const long stride = (long)gridDim.x * blockDim.x;
  for (long i = (long)blockIdx.x * blockDim.x + threadIdx.x; i < n4; i += stride) {
    float4 v = ((const float4*)p)[i];
    ushort4 h, l;
    cvt4split(v, h, l);
    ((ushort4*)ph)[i] = h;
    ((ushort4*)pl)[i] = l;
  }
}

// wb layout (elements): Wth@0, Wtl@EW, Wdb@2EW, W1b@3EW, W2b@4EW, Wd3b@5EW(+3EW)
__global__ __launch_bounds__(256) void k_prep_w(const float* __restrict__ Wt,
                                                const float* __restrict__ Wd,
                                                const float* __restrict__ Wd3,
                                                const float* __restrict__ W1,
                                                const float* __restrict__ W2,
                                                unsigned short* __restrict__ wb) {
  const int NW4 = EW / 4;
  const int stride = gridDim.x * blockDim.x;
  ushort4* Wth = (ushort4*)(wb);
  ushort4* Wtl = (ushort4*)(wb + EW);
  ushort4* Wdb = (ushort4*)(wb + 2 * EW);
  ushort4* W1b = (ushort4*)(wb + 3 * EW);
  ushort4* W2b = (ushort4*)(wb + 4 * EW);
  ushort4* Wd3b = (ushort4*)(wb + 5 * EW);
  for (int i = blockIdx.x * blockDim.x + threadIdx.x; i < NW4; i += stride) {
    float4 v = ((const float4*)Wt)[i];
    ushort4 h, l;
    cvt4split(v, h, l);
    Wth[i] = h;
    Wtl[i] = l;
    Wdb[i] = cvt4(((const float4*)Wd)[i]);
    W1b[i] = cvt4(((const float4*)W1)[i]);
    W2b[i] = cvt4(((const float4*)W2)[i]);
  }
  for (int i = blockIdx.x * blockDim.x + threadIdx.x; i < 3 * NW4; i += stride)
    Wd3b[i] = cvt4(((const float4*)Wd3)[i]);
}

// ---------------------------------------------------------------------------
// Tiled MFMA GEMM core, 2-phase double-buffered prefetch:
//   STAGE(t+1) is issued between the fragment reads and the MFMAs of tile t;
//   the single __syncthreads per tile is the wait (drains vmcnt+lgkm).
// C[128x128] = A[128xK] * B^T. B is [N,K] row-major. K/32 must be EVEN.
// ---------------------------------------------------------------------------
template <bool A_F32, bool B_F32>
__device__ __forceinline__ void gemm_tile(const void* __restrict__ Av, int lda,
                                          const void* __restrict__ Bv, int ldb, int K,
                                          f32x4 acc[4][4]) {
  __shared__ __align__(16) unsigned short As[2][128 * LDP];
  __shared__ __align__(16) unsigned short Bs[2][128 * LDP];
  const int tid = threadIdx.x;
  const int lane = tid & 63;
  const int wid = tid >> 6;
  const int wr = (wid >> 1) << 6;
  const int wc = (wid & 1) << 6;
  const int q4 = lane >> 4;
  const int l16 = lane & 15;

#pragma unroll
  for (int mi = 0; mi < 4; ++mi)
#pragma unroll
    for (int ni = 0; ni < 4; ++ni) acc[mi][ni] = (f32x4){0.f, 0.f, 0.f, 0.f};

  auto STAGE = [&](int kk, int bi) {
    if constexpr (A_F32)
      stage_f32<128>((const float*)Av, lda, kk, As[bi], tid);
    else
      dma_b16<128>((const unsigned short*)Av, lda, kk, As[bi], tid);
    if constexpr (B_F32)
      stage_f32<128>((const float*)Bv, ldb, kk, Bs[bi], tid);
    else
      dma_b16<128>((const unsigned short*)Bv, ldb, kk, Bs[bi], tid);
  };
  bf16x8 af[4], bfr[4];
  auto READF = [&](int bi) {
#pragma unroll
    for (int mi = 0; mi < 4; ++mi) {
      int rr = wr + mi * 16 + l16;
      af[mi] = *(const bf16x8*)(&As[bi][rr * LDP + ((q4 << 3) ^ swz8(rr))]);
    }
#pragma unroll
    for (int ni = 0; ni < 4; ++ni) {
      int rr = wc + ni * 16 + l16;
      bfr[ni] = *(const bf16x8*)(&Bs[bi][rr * LDP + ((q4 << 3) ^ swz8(rr))]);
    }
  };
  auto DOMFMA = [&]() {
#pragma unroll
    for (int mi = 0; mi < 4; ++mi)
#pragma unroll
      for (int ni = 0; ni < 4; ++ni)
        acc[mi][ni] =
            __builtin_amdgcn_mfma_f32_16x16x32_bf16(af[mi], bfr[ni], acc[mi][ni], 0, 0, 0);
  };

  const int ns = K >> 5;  // even for all call sites (8, 24, 72)
  STAGE(0, 0);
  for (int i = 0; i < ns; i += 2) {
    __syncthreads();
    READF(0);
    STAGE((i + 1) << 5, 1);
    DOMFMA();
    __syncthreads();
    READF(1);
    if (i + 2 < ns) STAGE((i + 2) << 5, 0);
    DOMFMA();
  }
}

// Split-precision GEMM core (fallback only): A precast hi/lo bf16 (DMA);
// B fp32 split-staged on the fly. Single-buffered (original structure).
__device__ __forceinline__ void gemm_tile_split(const unsigned short* __restrict__ Ahp,
                                                const unsigned short* __restrict__ Alp, int lda,
                                                const float* __restrict__ B, int ldb, int K,
                                                f32x4 acc[4][4]) {
  __shared__ __align__(16) unsigned short Ah[128 * LDP], Al[128 * LDP];
  __shared__ __align__(16) unsigned short Bh[128 * LDP], Bl[128 * LDP];
  const int tid = threadIdx.x;
  const int lane = tid & 63;
  const int wid = tid >> 6;
  const int wr = (wid >> 1) << 6;
  const int wc = (wid & 1) << 6;
  const int q4 = lane >> 4;
  const int l16 = lane & 15;

#pragma unroll
  for (int mi = 0; mi < 4; ++mi)
#pragma unroll
    for (int ni = 0; ni < 4; ++ni) acc[mi][ni] = (f32x4){0.f, 0.f, 0.f, 0.f};

  for (int kk = 0; kk < K; kk += 32) {
    __syncthreads();
    dma_b16<128>(Ahp, lda, kk, Ah, tid);
    dma_b16<128>(Alp, lda, kk, Al, tid);
    stage_f32_split<128>(B, ldb, kk, Bh, Bl, tid);
    __syncthreads();
    bf16x8 ah[4], al[4], bh[4], bl[4];
#pragma unroll
    for (int mi = 0; mi < 4; ++mi) {
      int rr = wr + mi * 16 + l16;
      int co = (q4 << 3) ^ swz8(rr);
      ah[mi] = *(const bf16x8*)(&Ah[rr * LDP + co]);
      al[mi] = *(const bf16x8*)(&Al[rr * LDP + co]);
    }
#pragma unroll
    for (int ni = 0; ni < 4; ++ni) {
      int rr = wc + ni * 16 + l16;
      int co = (q4 << 3) ^ swz8(rr);
      bh[ni] = *(const bf16x8*)(&Bh[rr * LDP + co]);
      bl[ni] = *(const bf16x8*)(&Bl[rr * LDP + co]);
    }
#pragma unroll
    for (int mi = 0; mi < 4; ++mi)
#pragma unroll
      for (int ni = 0; ni < 4; ++ni) {
        acc[mi][ni] =
            __builtin_amdgcn_mfma_f32_16x16x32_bf16(ah[mi], bh[ni], acc[mi][ni], 0, 0, 0);
        acc[mi][ni] =
            __builtin_amdgcn_mfma_f32_16x16x32_bf16(ah[mi], bl[ni], acc[mi][ni], 0, 0, 0);
        acc[mi][ni] =
            __builtin_amdgcn_mfma_f32_16x16x32_bf16(al[mi], bh[ni], acc[mi][ni], 0, 0, 0);
      }
  }
}

// Split-precision GEMM core: A and B both precast hi/lo bf16, all-DMA,
// 2-phase double-buffered prefetch. K/32 must be EVEN.
__device__ __forceinline__ void gemm_tile_split_b16(const unsigned short* __restrict__ Ahp,
                                                    const unsigned short* __restrict__ Alp, int lda,
                                                    const unsigned short* __restrict__ Bhp,
                                                    const unsigned short* __restrict__ Blp, int ldb,
                                                    int K, f32x4 acc[4][4]) {
  __shared__ __align__(16) unsigned short Ah[2][128 * LDP], Al[2][128 * LDP];
  __shared__ __align__(16) unsigned short Bh[2][128 * LDP], Bl[2][128 * LDP];
  const int tid = threadIdx.x;
  const int lane = tid & 63;
  const int wid = tid >> 6;
  const int wr = (wid >> 1) << 6;
  const int wc = (wid & 1) << 6;
  const int q4 = lane >> 4;
  const int l16 = lane & 15;

#pragma unroll
  for (int mi = 0; mi < 4; ++mi)
#pragma unroll
    for (int ni = 0; ni < 4; ++ni) acc[mi][ni] = (f32x4){0.f, 0.f, 0.f, 0.f};

  auto STAGE = [&](int kk, int bi) {
    dma_b16<128>(Ahp, lda, kk, Ah[bi], tid);
    dma_b16<128>(Alp, lda, kk, Al[bi], tid);
    dma_b16<128>(Bhp, ldb, kk, Bh[bi], tid);
    dma_b16<128>(Blp, ldb, kk, Bl[bi], tid);
  };
  bf16x8 ah[4], al[4], bh[4], bl[4];
  auto READF = [&](int bi) {
#pragma unroll
    for (int mi = 0; mi < 4; ++mi) {
      int rr = wr + mi * 16 + l16;
      int co = (q4 << 3) ^ swz8(rr);
      ah[mi] = *(const bf16x8*)(&Ah[bi][rr * LDP + co]);
      al[mi] = *(const bf16x8*)(&Al[bi][rr * LDP + co]);
    }
#pragma unroll
    for (int ni = 0; ni < 4; ++ni) {
      int rr = wc + ni * 16 + l16;
      int co = (q4 << 3) ^ swz8(rr);
      bh[ni] = *(const bf16x8*)(&Bh[bi][rr * LDP + co]);
      bl[ni] = *(const bf16x8*)(&Bl[bi][rr * LDP + co]);
    }
  };
  auto DOMFMA = [&]() {
#pragma unroll
    for (int mi = 0; mi < 4; ++mi)
#pragma unroll
      for (int ni = 0; ni < 4; ++ni) {
        acc[mi][ni] =
            __builtin_amdgcn_mfma_f32_16x16x32_bf16(ah[mi], bh[ni], acc[mi][ni], 0, 0, 0);
        acc[mi][ni] =
            __builtin_amdgcn_mfma_f32_16x16x32_bf16(ah[mi], bl[ni], acc[mi][ni], 0, 0, 0);
        acc[mi][ni] =
            __builtin_amdgcn_mfma_f32_16x16x32_bf16(al[mi], bh[ni], acc[mi][ni], 0, 0, 0);
      }
  };

  const int ns = K >> 5;  // 24
  STAGE(0, 0);
  for (int i = 0; i < ns; i += 2) {
    __syncthreads();
    READF(0);
    STAGE((i + 1) << 5, 1);
    DOMFMA();
    __syncthreads();
    READF(1);
    if (i + 2 < ns) STAGE((i + 2) << 5, 0);
    DOMFMA();
  }
}

// C/D layout (m89-verified): col=lane&15, row=(lane>>4)*4+reg.
#define EPI_BEGIN()                                        \
  const int lane = threadIdx.x & 63;                       \
  const int wid = threadIdx.x >> 6;                        \
  const int wr = (wid >> 1) << 6, wc = (wid & 1) << 6;     \
  const int q4 = lane >> 4, l16 = lane & 15;               \
  _Pragma("unroll") for (int mi = 0; mi < 4; ++mi)         \
      _Pragma("unroll") for (int ni = 0; ni < 4; ++ni)

// ---------------------------------------------------------------------------
// K1: tp = p @ Wt^T + bt  (split precision, stored as hi/lo bf16 pair)
template <bool WF32>
__global__ __launch_bounds__(256) void k_tp(const unsigned short* __restrict__ ph,
                                            const unsigned short* __restrict__ pl,
                                            const void* __restrict__ Wh,
                                            const void* __restrict__ Wl,
                                            const float* __restrict__ bt,
                                            unsigned short* __restrict__ tph,
                                            unsigned short* __restrict__ tpl) {
  const int bm = blockIdx.x * 128, bn = blockIdx.y * 128;
  f32x4 acc[4][4];
  if constexpr (WF32)
    gemm_tile_split(ph + (long)bm * Hq, pl + (long)bm * Hq, Hq,
                    (const float*)Wh + (long)bn * Hq, Hq, Hq, acc);
  else
    gemm_tile_split_b16(ph + (long)bm * Hq, pl + (long)bm * Hq, Hq,
                        (const unsigned short*)Wh + (long)bn * Hq,
                        (const unsigned short*)Wl + (long)bn * Hq, Hq, Hq, acc);
  const bool has_lo = (tpl != nullptr);
  EPI_BEGIN() {
    int col = bn + wc + ni * 16 + l16;
    float bv = bt[col];
#pragma unroll
    for (int r = 0; r < 4; ++r) {
      int row = bm + wr + mi * 16 + q4 * 4 + r;
      float v = acc[mi][ni][r] + bv;
      unsigned short h = f2bf(v);
      tph[(long)row * Hq + col] = h;
      if (has_lo) tpl[(long)row * Hq + col] = f2bf(v - bf2f(h));
    }
  }
}

// K2: pdT[b][h][s] = (p @ Wd^T)[b*256+s][h]  (transposed store; bd added in k_occ)
template <bool WF32>
__global__ __launch_bounds__(256) void k_pd(const unsigned short* __restrict__ ph,
                                            const void* __restrict__ Wd,
                                            unsigned short* __restrict__ pdT) {
  const int bm = blockIdx.x * 128, bn = blockIdx.y * 128;
  f32x4 acc[4][4];
  if constexpr (WF32)
    gemm_tile<false, true>(ph + (long)bm * Hq, Hq, (const float*)Wd + (long)bn * Hq, Hq, Hq, acc);
  else
    gemm_tile<false, false>(ph + (long)bm * Hq, Hq, (const unsigned short*)Wd + (long)bn * Hq,
                            Hq, Hq, acc);
  EPI_BEGIN() {
    int col = bn + wc + ni * 16 + l16;          // h index
    int rbase = bm + wr + mi * 16 + (q4 << 2);  // global row = b*256 + s
    int b = rbase >> 8, s0 = rbase & 255;
    ushort4 o;
    o.x = f2bf(acc[mi][ni][0]);
    o.y = f2bf(acc[mi][ni][1]);
    o.z = f2bf(acc[mi][ni][2]);
    o.w = f2bf(acc[mi][ni][3]);
    *(ushort4*)(pdT + ((long)b * Hq + col) * Sq + s0) = o;
  }
}

// ---------------------------------------------------------------------------
// K3 (fused): sm[b,k] = masked_softmax(p[b] @ tp[j]^T)  -> bf16 [384,256,256]
// Split-precision scores: p hi/lo (direct global->reg) x tp hi/lo (LDS,
// double-buffered DMA with prefetch-before-compute).
// Block: 128 rows x 256 cols. 4 waves: 2 row-groups x 2 col-halves.
// XCD-swizzled block order for group-local tp reuse in per-XCD L2.
// ---------------------------------------------------------------------------
__global__ __launch_bounds__(256, 2) void k_attsm(const unsigned short* __restrict__ ph,
                                                  const unsigned short* __restrict__ pl,
                                                  const unsigned short* __restrict__ tph,
                                                  const unsigned short* __restrict__ tpl,
                                                  const int* __restrict__ olen,
                                                  unsigned short* __restrict__ sm) {
  // Bijective XCD swizzle: 768 blocks = 8 XCDs x 96 chunks.
  const int lin = blockIdx.x + 2 * blockIdx.y;
  const int w = (lin & 7) * 96 + (lin >> 3);
  const int batch = w >> 1;
  const int bm = (w & 1) * 128;

  const int b = batch / 3, k = batch % 3;
  const int j = other_of(b, k);
  const int len = olen[j] + 1;  // key length, 1..255
  const int tid = threadIdx.x;
  const int lane = tid & 63;
  const int wid = tid >> 6;
  const int wr = (wid >> 1) << 6;  // 0 or 64
  const int wc = (wid & 1) << 7;   // 0 or 128
  const int half = wid & 1;
  const int q4 = lane >> 4, l16 = lane & 15;
  const bool has_lo = (tpl != nullptr);

  __shared__ __align__(16) unsigned short Bh[2][256 * LDP], Bl[2][256 * LDP];
  __shared__ float red[256];  // 128 rows x 2 column-halves

  const unsigned short* Aph = ph + ((long)b * Sq + bm) * Hq;
  const unsigned short* Apl = pl + ((long)b * Sq + bm) * Hq;
  const unsigned short* Bph = tph + (long)j * Sq * Hq;
  const unsigned short* Bpl = has_lo ? tpl + (long)j * Sq * Hq : nullptr;

  f32x4 acc[4][8];
#pragma unroll
  for (int mi = 0; mi < 4; ++mi)
#pragma unroll
    for (int ni = 0; ni < 8; ++ni) acc[mi][ni] = (f32x4){0.f, 0.f, 0.f, 0.f};

  auto STAGE_B = [&](int kk, int bi) {
    dma_b16<256>(Bph, Hq, kk, Bh[bi], tid);
    if (has_lo) dma_b16<256>(Bpl, Hq, kk, Bl[bi], tid);
  };
  bf16x8 ah[4], al[4];
  auto LOADA = [&](int kk) {
#pragma unroll
    for (int mi = 0; mi < 4; ++mi) {
      long off = (long)(wr + mi * 16 + l16) * Hq + kk + (q4 << 3);
      ah[mi] = *(const bf16x8*)(Aph + off);
      al[mi] = *(const bf16x8*)(Apl + off);
    }
  };
  auto COMPUTE = [&](int bi) {
#pragma unroll
    for (int ni = 0; ni < 8; ++ni) {
      int rr = wc + ni * 16 + l16;
      int co = (q4 << 3) ^ swz8(rr);
      bf16x8 bh = *(const bf16x8*)(&Bh[bi][rr * LDP + co]);
#pragma unroll
      for (int mi = 0; mi < 4; ++mi) {
        acc[mi][ni] = __builtin_amdgcn_mfma_f32_16x16x32_bf16(ah[mi], bh, acc[mi][ni], 0, 0, 0);
        acc[mi][ni] = __builtin_amdgcn_mfma_f32_16x16x32_bf16(al[mi], bh, acc[mi][ni], 0, 0, 0);
      }
      if (has_lo) {
        bf16x8 bl = *(const bf16x8*)(&Bl[bi][rr * LDP + co]);
#pragma unroll
        for (int mi = 0; mi < 4; ++mi)
          acc[mi][ni] = __builtin_amdgcn_mfma_f32_16x16x32_bf16(ah[mi], bl, acc[mi][ni], 0, 0, 0);
      }
    }
  };

  const int ns = Hq / 32;  // 24, even
  STAGE_B(0, 0);
  for (int i = 0; i < ns; i += 2) {
    __syncthreads();
    LOADA(i << 5);
    STAGE_B((i + 1) << 5, 1);
    COMPUTE(0);
    __syncthreads();
    LOADA((i + 1) << 5);
    if (i + 2 < ns) STAGE_B((i + 2) << 5, 0);
    COMPUTE(1);
  }

  // ---- reference-faithful masked softmax, numerically stable ----
  bool cm[8];
#pragma unroll
  for (int ni = 0; ni < 8; ++ni) cm[ni] = (wc + ni * 16 + l16) >= len;
#pragma unroll
  for (int mi = 0; mi < 4; ++mi)
#pragma unroll
    for (int ni = 0; ni < 8; ++ni)
      if (cm[ni]) acc[mi][ni] = (f32x4){0.f, 0.f, 0.f, 0.f};  // score*mask

  float rmax[4][4];
#pragma unroll
  for (int mi = 0; mi < 4; ++mi)
#pragma unroll
    for (int r = 0; r < 4; ++r) {
      float m = acc[mi][0][r];
#pragma unroll
      for (int ni = 1; ni < 8; ++ni) m = fmaxf(m, acc[mi][ni][r]);
#pragma unroll
      for (int off = 1; off <= 8; off <<= 1) m = fmaxf(m, __shfl_xor(m, off, 64));
      rmax[mi][r] = m;  // max over this col-half (includes masked zeros)
    }
  __syncthreads();  // K-loop LDS reads fully retired before red reuse below
  if (l16 == 0) {
#pragma unroll
    for (int mi = 0; mi < 4; ++mi)
#pragma unroll
      for (int r = 0; r < 4; ++r) red[(wr + mi * 16 + q4 * 4 + r) * 2 + half] = rmax[mi][r];
  }
  __syncthreads();
#pragma unroll
  for (int mi = 0; mi < 4; ++mi)
#pragma unroll
    for (int r = 0; r < 4; ++r) {
      int row = wr + mi * 16 + q4 * 4 + r;
      rmax[mi][r] = fmaxf(red[row * 2], red[row * 2 + 1]);
    }
  __syncthreads();  // red reads done before reuse

  // su = sum of exp over UNMASKED entries only (stable).
  float rsum[4][4];
#pragma unroll
  for (int mi = 0; mi < 4; ++mi)
#pragma unroll
    for (int r = 0; r < 4; ++r) rsum[mi][r] = 0.f;
#pragma unroll
  for (int mi = 0; mi < 4; ++mi)
#pragma unroll
    for (int ni = 0; ni < 8; ++ni)
#pragma unroll
      for (int r = 0; r < 4; ++r) {
        float e = __expf(acc[mi][ni][r] - rmax[mi][r]);
        acc[mi][ni][r] = e;
        if (!cm[ni]) rsum[mi][r] += e;
      }
#pragma unroll
  for (int mi = 0; mi < 4; ++mi)
#pragma unroll
    for (int r = 0; r < 4; ++r) {
#pragma unroll
      for (int off = 1; off <= 8; off <<= 1) rsum[mi][r] += __shfl_xor(rsum[mi][r], off, 64);
    }
  if (l16 == 0) {
#pragma unroll
    for (int mi = 0; mi < 4; ++mi)
#pragma unroll
      for (int r = 0; r < 4; ++r) red[(wr + mi * 16 + q4 * 4 + r) * 2 + half] = rsum[mi][r];
  }
  __syncthreads();

  const float nm = (float)(Sq - len);
  unsigned short* srow = sm + (long)batch * Sq * Sq;
#pragma unroll
  for (int mi = 0; mi < 4; ++mi)
#pragma unroll
    for (int r = 0; r < 4; ++r) {
      int row = wr + mi * 16 + q4 * 4 + r;
      float su = red[row * 2] + red[row * 2 + 1];  // unmasked sum (>=0)
      float em = __expf(-rmax[mi][r]);             // masked entries' e
      float zs = su + nm * em;                     // full softmax denom
      float fs = 1.f / (su + 1e-13f * zs);         // stable renorm
      unsigned short* o = srow + (long)(bm + row) * Sq + wc + l16;
#pragma unroll
      for (int ni = 0; ni < 8; ++ni)
        o[ni * 16] = f2bf(cm[ni] ? 0.f : acc[mi][ni][r] * fs);
    }
}

// K4: occ[(b,s,k),:] = relu(sm[b,k] @ pd[j] + bd)   rows in (b,s,k) order
// pd consumed via pdT[j][h][s]: B[N=h,K=s] row-major -> DMA staging.
// XCD-swizzled block order for batch-local sm/pdT reuse in per-XCD L2.
__global__ __launch_bounds__(256) void k_occ(const unsigned short* __restrict__ sm,
                                             const unsigned short* __restrict__ pdT,
                                             const float* __restrict__ bd,
                                             unsigned short* __restrict__ occ) {
  // Bijective XCD swizzle: 4608 blocks = 8 XCDs x 576 chunks.
  const int lin = blockIdx.x + 2 * (blockIdx.y + 6 * blockIdx.z);
  const int w = (lin & 7) * 576 + (lin >> 3);
  const int t = w >> 1;
  const int bm = (w & 1) * 128, bn = (t % 6) * 128;
  const int batch = t / 6;

  const int b = batch / 3, k = batch % 3;
  const int j = other_of(b, k);
  f32x4 acc[4][4];
  gemm_tile<false, false>(sm + (long)batch * Sq * Sq + (long)bm * Sq, Sq,
                          pdT + ((long)j * Hq + bn) * Sq, Sq, Sq, acc);
  EPI_BEGIN() {
    int col = bn + wc + ni * 16 + l16;
    float bv = bd[col];
#pragma unroll
    for (int r = 0; r < 4; ++r) {
      int s = bm + wr + mi * 16 + q4 * 4 + r;
      occ[((long)(b * Sq + s) * 3 + k) * Hq + col] = f2bf(fmaxf(acc[mi][ni][r] + bv, 0.f));
    }
  }
}

// K5: oc = occ_flat[32768,2304] @ Wd3^T + bd3  -> bf16
template <bool WF32>
__global__ __launch_bounds__(256) void k_oc(const unsigned short* __restrict__ occ,
                                            const void* __restrict__ Wd3,
                                            const float* __restrict__ bd3,
                                            unsigned short* __restrict__ oc) {
  const int bm = blockIdx.x * 128, bn = blockIdx.y * 128;
  f32x4 acc[4][4];
  if constexpr (WF32)
    gemm_tile<false, true>(occ + (long)bm * 3 * Hq, 3 * Hq,
                           (const float*)Wd3 + (long)bn * 3 * Hq, 3 * Hq, 3 * Hq, acc);
  else
    gemm_tile<false, false>(occ + (long)bm * 3 * Hq, 3 * Hq,
                            (const unsigned short*)Wd3 + (long)bn * 3 * Hq, 3 * Hq, 3 * Hq, acc);
  EPI_BEGIN() {
    int col = bn + wc + ni * 16 + l16;
    float bv = bd3[col];
#pragma unroll
    for (int r = 0; r < 4; ++r) {
      int row = bm + wr + mi * 16 + q4 * 4 + r;
      oc[(long)row * Hq + col] = f2bf(acc[mi][ni][r] + bv);
    }
  }
}

// K6: g1 = oc @ W1^T + b1 + b2  -> bf16
template <bool WF32>
__global__ __launch_bounds__(256) void k_g1(const unsigned short* __restrict__ oc,
                                            const void* __restrict__ W1,
                                            const float* __restrict__ b1,
                                            const float* __restrict__ b2,
                                            unsigned short* __restrict__ g1) {
  const int bm = blockIdx.x * 128, bn = blockIdx.y * 128;
  f32x4 acc[4][4];
  if constexpr (WF32)
    gemm_tile<false, true>(oc + (long)bm * Hq, Hq, (const float*)W1 + (long)bn * Hq, Hq, Hq, acc);
  else
    gemm_tile<false, false>(oc + (long)bm * Hq, Hq, (const unsigned short*)W1 + (long)bn * Hq,
                            Hq, Hq, acc);
  EPI_BEGIN() {
    int col = bn + wc + ni * 16 + l16;
    float bv = b1[col] + b2[col];
#pragma unroll
    for (int r = 0; r < 4; ++r) {
      int row = bm + wr + mi * 16 + q4 * 4 + r;
      g1[(long)row * Hq + col] = f2bf(acc[mi][ni][r] + bv);
    }
  }
}

// K7: mid = sigmoid(g1 + p @ W2^T); out = p*mid + oc*(1-mid)  (fp32 out)
template <bool WF32>
__global__ __launch_bounds__(256) void k_out(const float* __restrict__ p,
                                             const void* __restrict__ W2,
                                             const unsigned short* __restrict__ g1,
                                             const unsigned short* __restrict__ oc,
                                             float* __restrict__ out) {
  const int bm = blockIdx.x * 128, bn = blockIdx.y * 128;
  f32x4 acc[4][4];
  if constexpr (WF32)
    gemm_tile<true, true>(p + (long)bm * Hq, Hq, (const float*)W2 + (long)bn * Hq, Hq, Hq, acc);
  else
    gemm_tile<true, false>(p + (long)bm * Hq, Hq, (const unsigned short*)W2 + (long)bn * Hq,
                           Hq, Hq, acc);
  EPI_BEGIN() {
    int col = bn + wc + ni * 16 + l16;
#pragma unroll
    for (int r = 0; r < 4; ++r) {
      int row = bm + wr + mi * 16 + q4 * 4 + r;
      long idx = (long)row * Hq + col;
      float g = acc[mi][ni][r] + bf2f(g1[idx]);
      float mid = 1.f / (1.f + __expf(-g));
      float pv = p[idx];
      float ov = bf2f(oc[idx]);
      out[idx] = pv * mid + ov * (1.f - mid);
    }
  }
}

// ---------------------------------------------------------------------------
extern "C" void kernel_launch(void* const* d_in, const int* in_sizes, int n_in, void* d_out,
                              int out_size, void* d_ws, size_t ws_size, hipStream_t stream) {
  const float* p = (const float*)d_in[0];
  const int* olen = (const int*)d_in[1];
  const float* Wt = (const float*)d_in[2];
  const float* bt = (const float*)d_in[3];
  const float* Wd = (const float*)d_in[4];
  const float* bd = (const float*)d_in[5];
  const float* Wd3 = (const float*)d_in[6];
  const float* bd3 = (const float*)d_in[7];
  const float* W1 = (const float*)d_in[8];
  const float* b1 = (const float*)d_in[9];
  const float* W2 = (const float*)d_in[10];
  const float* b2 = (const float*)d_in[11];
  float* out = (float*)d_out;

  char* ws = (char*)d_ws;
  const long U = 50331648L;   // 48 MiB unit
  const long WB = 9437184L;   // 9 MiB precast-weight block

  if (ws_size >= (size_t)(WB + 5 * U)) {
    // 249 MiB layout (byte offsets, MiB):
    //   wb   0..9    (prep_w -> K7)          precast weights
    //   ph   9..57   (prep_p -> k_pd)
    //   pl   57..105 (prep_p -> k_attsm)
    //   tph  105..153 (k_tp -> k_attsm)
    //   tpl  153..201 (k_tp -> k_attsm)
    //   sm   201..249 (k_attsm -> k_occ)
    //   pdT  153..201 (k_pd -> k_occ)        [k_pd runs AFTER k_attsm]
    //   occ  9..153  (k_occ -> k_oc)         [ph,pl,tph dead by then]
    //   oc   153..201 (k_oc -> k_out)        [pdT dead]
    //   g1   201..249 (k_g1 -> k_out)        [sm dead]
    unsigned short* wb = (unsigned short*)(ws);
    unsigned short* ph = (unsigned short*)(ws + WB);
    unsigned short* pl = (unsigned short*)(ws + WB + 1 * U);
    unsigned short* tph = (unsigned short*)(ws + WB + 2 * U);
    unsigned short* tpl = (unsigned short*)(ws + WB + 3 * U);
    unsigned short* sm = (unsigned short*)(ws + WB + 4 * U);
    unsigned short* pdT = (unsigned short*)(ws + WB + 3 * U);
    unsigned short* occ = (unsigned short*)(ws + WB);
    unsigned short* oc = (unsigned short*)(ws + WB + 3 * U);
    unsigned short* g1 = (unsigned short*)(ws + WB + 4 * U);

    k_prep_p<<<2048, 256, 0, stream>>>(p, ph, pl);
    k_prep_w<<<512, 256, 0, stream>>>(Wt, Wd, Wd3, W1, W2, wb);
    k_tp<false><<<dim3(256, 6), 256, 0, stream>>>(ph, pl, wb, wb + EW, bt, tph, tpl);
    k_attsm<<<dim3(2, 384), 256, 0, stream>>>(ph, pl, tph, tpl, olen, sm);
    k_pd<false><<<dim3(256, 6), 256, 0, stream>>>(ph, wb + 2 * EW, pdT);
    k_occ<<<dim3(2, 6, 384), 256, 0, stream>>>(sm, pdT, bd, occ);
    k_oc<false><<<dim3(256, 6), 256, 0, stream>>>(occ, wb + 5 * EW, bd3, oc);
    k_g1<false><<<dim3(256, 6), 256, 0, stream>>>(oc, wb + 3 * EW, b1, b2, g1);
    k_out<false><<<dim3(256, 6), 256, 0, stream>>>(p, wb + 4 * EW, g1, oc, out);
  } else {
    // 240 MiB fallback: drop tp_lo, fp32 weights staged on the fly.
    //   slot0: tph, occ   slot1: ph, occ   slot2: pl, occ
    //   slot3: pdT (K2->K4), oc (K5->K7)   slot4: sm, g1
    unsigned short* tph = (unsigned short*)(ws + 0 * U);
    unsigned short* tpl = nullptr;
    unsigned short* ph = (unsigned short*)(ws + 1 * U);
    unsigned short* pl = (unsigned short*)(ws + 2 * U);
    unsigned short* occ = (unsigned short*)(ws + 0 * U);
    unsigned short* pdT = (unsigned short*)(ws + 3 * U);
    unsigned short* oc = (unsigned short*)(ws + 3 * U);
    unsigned short* sm = (unsigned short*)(ws + 4 * U);
    unsigned short* g1 = (unsigned short*)(ws + 4 * U);

    k_prep_p<<<2048, 256, 0, stream>>>(p, ph, pl);
    k_tp<true><<<dim3(256, 6), 256, 0, stream>>>(ph, pl, Wt, nullptr, bt, tph, tpl);
    k_pd<true><<<dim3(256, 6), 256, 0, stream>>>(ph, Wd, pdT);
    k_attsm<<<dim3(2, 384), 256, 0, stream>>>(ph, pl, tph, tpl, olen, sm);
    k_occ<<<dim3(2, 6, 384), 256, 0, stream>>>(sm, pdT, bd, occ);
    k_oc<true><<<dim3(256, 6), 256, 0, stream>>>(occ, Wd3, bd3, oc);
    k_g1<true><<<dim3(256, 6), 256, 0, stream>>>(oc, W1, b1, b2, g1);
    k_out<true><<<dim3(256, 6), 256, 0, stream>>>(p, W2, g1, oc, out);
  }
}